// Round 11
// baseline (163.927 us; speedup 1.0000x reference)
//
#include <hip/hip_runtime.h>
#include <stdint.h>

typedef short bf16x8 __attribute__((ext_vector_type(8)));
typedef float f32x4  __attribute__((ext_vector_type(4)));

#define LOG2E_F 1.4426950408889634f
// 0.125 * log2(e): folded into Q so exp2 args need no multiply
#define QSCALE_F 0.1803368801111204f

__device__ __forceinline__ unsigned short f2bf(float f) {
    unsigned int u = __float_as_uint(f);
    return (unsigned short)((u + 0x7FFFu + ((u >> 16) & 1u)) >> 16);
}

// fast pack for non-negative, non-NaN values (round-half-up)
__device__ __forceinline__ unsigned short f2bfu(float f) {
    return (unsigned short)((__float_as_uint(f) + 0x8000u) >> 16);
}

__device__ __forceinline__ uint4 pack8(float4 a, float4 b) {
    union { unsigned short us[8]; uint4 v; } p;
    p.us[0] = f2bf(a.x); p.us[1] = f2bf(a.y); p.us[2] = f2bf(a.z); p.us[3] = f2bf(a.w);
    p.us[4] = f2bf(b.x); p.us[5] = f2bf(b.y); p.us[6] = f2bf(b.z); p.us[7] = f2bf(b.w);
    return p.v;
}

// ===================== 0. f32 -> bf16 convert (X, in_proj_w, out_w) =====================
__global__ __launch_bounds__(256)
void cvt_kernel(const float* __restrict__ q, const float* __restrict__ k,
                const float* __restrict__ v, const float* __restrict__ w,
                const float* __restrict__ ow,
                uint4* __restrict__ Xb, uint4* __restrict__ Wb, uint4* __restrict__ OWb)
{
    const unsigned g = blockIdx.x * 256 + threadIdx.x;   // 0 .. 2097151
    const float* src;
    uint4* dst;
    if (g < 1572864u) {
        dst = Xb + g;
        if (g < 524288u)        src = q + (size_t)g * 8;
        else if (g < 1048576u)  src = k + (size_t)(g - 524288u) * 8;
        else                    src = v + (size_t)(g - 1048576u) * 8;
    } else if (g < 1966080u) {
        src = w + (size_t)(g - 1572864u) * 8;
        dst = Wb + (g - 1572864u);
    } else {
        src = ow + (size_t)(g - 1966080u) * 8;
        dst = OWb + (g - 1966080u);
    }
    float4 a = *(const float4*)src;
    float4 b = *(const float4*)(src + 4);
    *dst = pack8(a, b);
}

// ===================== 1. QKV projection GEMM (bf16 in, BK=64, prefetch) =====================
__global__ __launch_bounds__(256)
void qkv_proj_kernel(const unsigned short* __restrict__ Xb, const unsigned short* __restrict__ Wb,
                     const float* __restrict__ bias,
                     unsigned short* __restrict__ Qb, unsigned short* __restrict__ Kb,
                     unsigned short* __restrict__ Vtb)
{
    const int z = blockIdx.z;
    const int j   = blockIdx.x;           // 0..255
    const int xcd = j & 7, idx = j >> 3;  // idx 0..31
    const int row0 = ((xcd << 2) + (idx >> 3)) * 128;
    const int col0 = (idx & 7) * 128;
    const int wofs = z << 10;

    const unsigned short* A = Xb + (size_t)z * 4194304;
    const unsigned short* B = Wb;

    __shared__ __align__(16) unsigned short As[128 * 72];
    __shared__ __align__(16) unsigned short Bs[128 * 72];

    const int tid  = threadIdx.x;
    const int lane = tid & 63;
    const int wv   = tid >> 6;
    const int wr   = wv >> 1, wc = wv & 1;

    const f32x4 zero4 = {0.f, 0.f, 0.f, 0.f};
    f32x4 acc[4][4];
#pragma unroll
    for (int m = 0; m < 4; ++m)
#pragma unroll
        for (int n = 0; n < 4; ++n) acc[m][n] = zero4;

    const int srow = tid >> 1;
    const int scol = (tid & 1) << 5;
    const int arow = wr * 64 + (lane & 15);
    const int brow = wc * 64 + (lane & 15);
    const int kof  = (lane >> 4) << 3;

    const unsigned short* pa = A + (size_t)(row0 + srow) * 1024 + scol;
    const unsigned short* pb = B + (size_t)(wofs + col0 + srow) * 1024 + scol;
    uint4 ra0 = *(const uint4*)(pa + 0),  ra1 = *(const uint4*)(pa + 8);
    uint4 ra2 = *(const uint4*)(pa + 16), ra3 = *(const uint4*)(pa + 24);
    uint4 rb0 = *(const uint4*)(pb + 0),  rb1 = *(const uint4*)(pb + 8);
    uint4 rb2 = *(const uint4*)(pb + 16), rb3 = *(const uint4*)(pb + 24);

    for (int k0 = 0; k0 < 1024; k0 += 64) {
        __syncthreads();
        *(uint4*)&As[srow * 72 + scol]      = ra0;
        *(uint4*)&As[srow * 72 + scol + 8]  = ra1;
        *(uint4*)&As[srow * 72 + scol + 16] = ra2;
        *(uint4*)&As[srow * 72 + scol + 24] = ra3;
        *(uint4*)&Bs[srow * 72 + scol]      = rb0;
        *(uint4*)&Bs[srow * 72 + scol + 8]  = rb1;
        *(uint4*)&Bs[srow * 72 + scol + 16] = rb2;
        *(uint4*)&Bs[srow * 72 + scol + 24] = rb3;
        __syncthreads();

        if (k0 < 960) {
            pa = A + (size_t)(row0 + srow) * 1024 + k0 + 64 + scol;
            pb = B + (size_t)(wofs + col0 + srow) * 1024 + k0 + 64 + scol;
            ra0 = *(const uint4*)(pa + 0);  ra1 = *(const uint4*)(pa + 8);
            ra2 = *(const uint4*)(pa + 16); ra3 = *(const uint4*)(pa + 24);
            rb0 = *(const uint4*)(pb + 0);  rb1 = *(const uint4*)(pb + 8);
            rb2 = *(const uint4*)(pb + 16); rb3 = *(const uint4*)(pb + 24);
        }

#pragma unroll
        for (int kk = 0; kk < 2; ++kk) {
            bf16x8 af[4], bfr[4];
#pragma unroll
            for (int m = 0; m < 4; ++m)
                af[m] = *(const bf16x8*)&As[(arow + m * 16) * 72 + kk * 32 + kof];
#pragma unroll
            for (int n = 0; n < 4; ++n)
                bfr[n] = *(const bf16x8*)&Bs[(brow + n * 16) * 72 + kk * 32 + kof];
#pragma unroll
            for (int m = 0; m < 4; ++m)
#pragma unroll
                for (int n = 0; n < 4; ++n)
                    acc[m][n] = __builtin_amdgcn_mfma_f32_16x16x32_bf16(af[m], bfr[n], acc[m][n], 0, 0, 0);
        }
    }

    const int ccol = lane & 15;
    const int crow = (lane >> 4) << 2;
#pragma unroll
    for (int n = 0; n < 4; ++n) {
        const int gc   = col0 + wc * 64 + n * 16 + ccol;
        const float bv = bias[wofs + gc];
        const int head = gc >> 6, d = gc & 63;
#pragma unroll
        for (int m = 0; m < 4; ++m) {
#pragma unroll
            for (int r = 0; r < 4; ++r) {
                const int gr = row0 + wr * 64 + m * 16 + crow + r;
                const int t  = gr >> 2, b = gr & 3;
                const int bh = (b << 4) + head;
                float vv = acc[m][n][r] + bv;
                if (z == 0)      Qb [((size_t)bh << 16) + ((size_t)t << 6) + d]  = f2bf(vv * QSCALE_F);
                else if (z == 1) Kb [((size_t)bh << 16) + ((size_t)t << 6) + d]  = f2bf(vv);
                else             Vtb[((size_t)bh << 16) + ((size_t)d << 10) + t] = f2bf(vv);
            }
        }
    }
}

// ===================== 2. flash attention (swapped QK^T, P in registers, s-permuted V) =====================
// mfma(K,Q) -> lane holds full P row for t=lane&15 (s=16n+4g+r). PV A-fragment built lane-locally;
// V staged into LDS with matching s-permutation sigma(k): k=8g+j -> ls = j<4 ? 4g+j : 16+4g+(j-4).
// No Ps LDS, no cross-lane ops. Cross-round dbuf, 1 barrier/round. LDS 73.7 KB -> 2 blocks/CU.
__global__ __launch_bounds__(512)
void flash_kernel(const unsigned short* __restrict__ Qb, const unsigned short* __restrict__ Kb,
                  const unsigned short* __restrict__ Vtb, const float* __restrict__ attn_mask,
                  const int* __restrict__ padmask,
                  float* __restrict__ rl_buf, unsigned short* __restrict__ attn_out)
{
    const int j   = blockIdx.x;              // 0..511
    const int xcd = j & 7, idx = j >> 3;     // idx 0..63
    const int bh  = xcd * 8 + (idx >> 3);
    const int t0  = (idx & 7) << 7;
    const int b   = bh >> 4, h = bh & 15;

    __shared__ __align__(16) unsigned short Ks[2][2][64 * 72];  // [dbuf][tile] rows=s cols=d
    __shared__ __align__(16) unsigned short Vs[2][2][64 * 72];  // rows=d cols=sigma(s)

    const int tid  = threadIdx.x;
    const int lane = tid & 63;
    const int wv   = tid >> 6;               // 0..7
    const int kof  = (lane >> 4) << 3;
    const int c16  = lane & 15;
    const int g4   = (lane >> 4) << 2;

    const unsigned short* Qbase = Qb  + ((size_t)bh << 16);
    const unsigned short* Kbase = Kb  + ((size_t)bh << 16);
    const unsigned short* Vbase = Vtb + ((size_t)bh << 16);

    bf16x8 qf[2];
#pragma unroll
    for (int kk = 0; kk < 2; ++kk)
        qf[kk] = *(const bf16x8*)(Qbase + ((size_t)(t0 + wv * 16 + c16) << 6) + kk * 32 + kof);

    const bf16x8 ones = {16256, 16256, 16256, 16256, 16256, 16256, 16256, 16256};

    const f32x4 zero4 = {0.f, 0.f, 0.f, 0.f};
    f32x4 acco[4];
#pragma unroll
    for (int nd = 0; nd < 4; ++nd) acco[nd] = zero4;
    f32x4 acc_l = zero4;

    const int srow_st = tid >> 3;            // 0..63
    const int scol_st = (tid & 7) << 3;      // 0..56

    // V scatter columns: sigma^-1 of the 8 loaded s-values -> two contiguous b64 groups
    const int bb  = scol_st & 31;
    const int hh  = scol_st & 32;
    const int cL  = hh + ((bb & 15) >> 2) * 8 + (bb >> 4) * 4;
    const int bb4 = bb + 4;
    const int cH  = hh + ((bb4 & 15) >> 2) * 8 + (bb4 >> 4) * 4;

    const int tr2 = t0 + wv * 16 + c16;      // this lane's t-row (for mask gather)

    // ---- prologue: load round0 (tiles 0,1), stage into buf0, load round1 regs ----
    const unsigned short* kp = Kbase + ((size_t)srow_st << 6) + scol_st;
    const unsigned short* vp = Vbase + ((size_t)srow_st << 10) + scol_st;
    uint4 kA = *(const uint4*)kp;
    uint4 kB = *(const uint4*)(kp + 4096);
    uint4 vA = *(const uint4*)vp;
    uint4 vB = *(const uint4*)(vp + 64);

    {
        *(uint4*)&Ks[0][0][srow_st * 72 + scol_st] = kA;
        *(uint4*)&Ks[0][1][srow_st * 72 + scol_st] = kB;
        uint2 lo, hi;
        lo.x = vA.x; lo.y = vA.y; hi.x = vA.z; hi.y = vA.w;
        *(uint2*)&Vs[0][0][srow_st * 72 + cL] = lo;
        *(uint2*)&Vs[0][0][srow_st * 72 + cH] = hi;
        lo.x = vB.x; lo.y = vB.y; hi.x = vB.z; hi.y = vB.w;
        *(uint2*)&Vs[0][1][srow_st * 72 + cL] = lo;
        *(uint2*)&Vs[0][1][srow_st * 72 + cH] = hi;
    }
    kp = Kbase + ((size_t)(128 + srow_st) << 6) + scol_st;
    vp = Vbase + ((size_t)srow_st << 10) + 128 + scol_st;
    kA = *(const uint4*)kp;
    kB = *(const uint4*)(kp + 4096);
    vA = *(const uint4*)vp;
    vB = *(const uint4*)(vp + 64);
    __syncthreads();

    for (int rd = 0; rd < 8; ++rd) {
        const int cur = rd & 1;
        const int s0  = rd << 7;             // tile A at s0, tile B at s0+64

        if (rd < 7) {
            *(uint4*)&Ks[cur ^ 1][0][srow_st * 72 + scol_st] = kA;
            *(uint4*)&Ks[cur ^ 1][1][srow_st * 72 + scol_st] = kB;
            uint2 lo, hi;
            lo.x = vA.x; lo.y = vA.y; hi.x = vA.z; hi.y = vA.w;
            *(uint2*)&Vs[cur ^ 1][0][srow_st * 72 + cL] = lo;
            *(uint2*)&Vs[cur ^ 1][0][srow_st * 72 + cH] = hi;
            lo.x = vB.x; lo.y = vB.y; hi.x = vB.z; hi.y = vB.w;
            *(uint2*)&Vs[cur ^ 1][1][srow_st * 72 + cL] = lo;
            *(uint2*)&Vs[cur ^ 1][1][srow_st * 72 + cH] = hi;
        }
        if (rd < 6) {
            const int sn = s0 + 256;
            kp = Kbase + ((size_t)(sn + srow_st) << 6) + scol_st;
            vp = Vbase + ((size_t)srow_st << 10) + sn + scol_st;
            kA = *(const uint4*)kp;
            kB = *(const uint4*)(kp + 4096);
            vA = *(const uint4*)vp;
            vB = *(const uint4*)(vp + 64);
        }

        // QK^T swapped: accs[n] = mfma(K_frag, Q_frag) -> S[s=s0(+64)+16n+4g+r][t=tr2]
        f32x4 accsA[4], accsB[4];
#pragma unroll
        for (int n = 0; n < 4; ++n) { accsA[n] = zero4; accsB[n] = zero4; }
        __builtin_amdgcn_s_setprio(1);
#pragma unroll
        for (int n = 0; n < 4; ++n) {
            bf16x8 kfA0 = *(const bf16x8*)&Ks[cur][0][(n * 16 + c16) * 72 + kof];
            bf16x8 kfA1 = *(const bf16x8*)&Ks[cur][0][(n * 16 + c16) * 72 + 32 + kof];
            accsA[n] = __builtin_amdgcn_mfma_f32_16x16x32_bf16(kfA0, qf[0], accsA[n], 0, 0, 0);
            accsA[n] = __builtin_amdgcn_mfma_f32_16x16x32_bf16(kfA1, qf[1], accsA[n], 0, 0, 0);
            bf16x8 kfB0 = *(const bf16x8*)&Ks[cur][1][(n * 16 + c16) * 72 + kof];
            bf16x8 kfB1 = *(const bf16x8*)&Ks[cur][1][(n * 16 + c16) * 72 + 32 + kof];
            accsB[n] = __builtin_amdgcn_mfma_f32_16x16x32_bf16(kfB0, qf[0], accsB[n], 0, 0, 0);
            accsB[n] = __builtin_amdgcn_mfma_f32_16x16x32_bf16(kfB1, qf[1], accsB[n], 0, 0, 0);
        }
        __builtin_amdgcn_s_setprio(0);

#pragma unroll
        for (int tile = 0; tile < 2; ++tile) {
            const int s0t = s0 + tile * 64;
            f32x4* accs = tile ? accsB : accsA;

            // mask gather: float4 per n (r=0..3 contiguous); pad int4 per n
            float4 mk[4]; int4 pd[4];
#pragma unroll
            for (int n = 0; n < 4; ++n) {
                mk[n] = *(const float4*)(attn_mask + (size_t)tr2 * 1024 + s0t + n * 16 + g4);
                pd[n] = *(const int4*)(padmask + (b << 10) + s0t + n * 16 + g4);
            }

            union { unsigned short us[16]; bf16x8 v[2]; } pk;
#pragma unroll
            for (int n = 0; n < 4; ++n) {
                float x0 = fmaf(mk[n].x, LOG2E_F, accs[n][0]);
                float x1 = fmaf(mk[n].y, LOG2E_F, accs[n][1]);
                float x2 = fmaf(mk[n].z, LOG2E_F, accs[n][2]);
                float x3 = fmaf(mk[n].w, LOG2E_F, accs[n][3]);
                if (pd[n].x) x0 = -1e30f;
                if (pd[n].y) x1 = -1e30f;
                if (pd[n].z) x2 = -1e30f;
                if (pd[n].w) x3 = -1e30f;
                pk.us[n * 4 + 0] = f2bfu(__builtin_amdgcn_exp2f(x0));
                pk.us[n * 4 + 1] = f2bfu(__builtin_amdgcn_exp2f(x1));
                pk.us[n * 4 + 2] = f2bfu(__builtin_amdgcn_exp2f(x2));
                pk.us[n * 4 + 3] = f2bfu(__builtin_amdgcn_exp2f(x3));
            }

            // PV with s-permuted V: pfrag[h] covers s-half h (n=2h,2h+1)
            __builtin_amdgcn_s_setprio(1);
#pragma unroll
            for (int hhh = 0; hhh < 2; ++hhh) {
                bf16x8 pf = pk.v[hhh];
#pragma unroll
                for (int nd = 0; nd < 4; ++nd) {
                    bf16x8 vf = *(const bf16x8*)&Vs[cur][tile][(nd * 16 + c16) * 72 + hhh * 32 + kof];
                    acco[nd] = __builtin_amdgcn_mfma_f32_16x16x32_bf16(pf, vf, acco[nd], 0, 0, 0);
                }
                acc_l = __builtin_amdgcn_mfma_f32_16x16x32_bf16(pf, ones, acc_l, 0, 0, 0);
            }
            __builtin_amdgcn_s_setprio(0);
        }

        if (rd < 7) __syncthreads();
    }

#pragma unroll
    for (int r = 0; r < 4; ++r) {
        const int t = t0 + wv * 16 + g4 + r;
        const float rl = 1.0f / acc_l[r];
        if (c16 == 0)
            rl_buf[(bh << 10) + t] = rl;
#pragma unroll
        for (int nd = 0; nd < 4; ++nd) {
            const int d = nd * 16 + c16;
            attn_out[((size_t)t * 4 + b) * 1024 + h * 64 + d] = f2bf(acco[nd][r] * rl);
        }
    }
}

// ===================== 3. weights_avg (recompute scores, all heads) =====================
__global__ __launch_bounds__(256)
void wavg_kernel(const unsigned short* __restrict__ Qb, const unsigned short* __restrict__ Kb,
                 const float* __restrict__ attn_mask, const int* __restrict__ padmask,
                 const float* __restrict__ rl_buf, float* __restrict__ wout)
{
    const int j   = blockIdx.x;              // 0..1023
    const int xcd = j & 7;
    const int b   = xcd >> 1;
    const int rr  = ((j >> 3) << 1) + (xcd & 1);  // 0..255
    const int t0  = (rr >> 4) << 6;
    const int s0  = (rr & 15) << 6;

    __shared__ __align__(16) unsigned short Qs[64 * 72];
    __shared__ __align__(16) unsigned short Ks2[64 * 72];

    const int tid  = threadIdx.x;
    const int lane = tid & 63;
    const int wv   = tid >> 6;
    const int wr   = wv >> 1, wc = wv & 1;
    const int kof  = (lane >> 4) << 3;
    const int srow_st = tid >> 2;
    const int scol_st = (tid & 3) << 4;

    const int t_base = t0 + wr * 32 + ((lane >> 4) << 2);
    const int s_base = s0 + wc * 32 + (lane & 15);

    int pad2[2];
#pragma unroll
    for (int nn = 0; nn < 2; ++nn) pad2[nn] = padmask[(b << 10) + s_base + nn * 16];

    float maskv[2][2][4];
#pragma unroll
    for (int mm = 0; mm < 2; ++mm)
#pragma unroll
        for (int r = 0; r < 4; ++r)
#pragma unroll
            for (int nn = 0; nn < 2; ++nn)
                maskv[mm][nn][r] = attn_mask[(size_t)(t_base + mm * 16 + r) * 1024 + s_base + nn * 16] * LOG2E_F;

    float wsum[2][2][4];
#pragma unroll
    for (int mm = 0; mm < 2; ++mm)
#pragma unroll
        for (int nn = 0; nn < 2; ++nn)
#pragma unroll
            for (int r = 0; r < 4; ++r) wsum[mm][nn][r] = 0.f;

    for (int h = 0; h < 16; ++h) {
        const int bh = (b << 4) + h;
        __syncthreads();
        {
            const unsigned short* qp = Qb + ((size_t)bh << 16) + ((size_t)(t0 + srow_st) << 6) + scol_st;
            *(uint4*)&Qs[srow_st * 72 + scol_st]     = *(const uint4*)qp;
            *(uint4*)&Qs[srow_st * 72 + scol_st + 8] = *(const uint4*)(qp + 8);
            const unsigned short* kp = Kb + ((size_t)bh << 16) + ((size_t)(s0 + srow_st) << 6) + scol_st;
            *(uint4*)&Ks2[srow_st * 72 + scol_st]     = *(const uint4*)kp;
            *(uint4*)&Ks2[srow_st * 72 + scol_st + 8] = *(const uint4*)(kp + 8);
        }
        __syncthreads();

        float rlv[2][4];
#pragma unroll
        for (int mm = 0; mm < 2; ++mm)
#pragma unroll
            for (int r = 0; r < 4; ++r)
                rlv[mm][r] = rl_buf[(bh << 10) + t_base + mm * 16 + r];

        const f32x4 zero4 = {0.f, 0.f, 0.f, 0.f};
        f32x4 accs[2][2];
#pragma unroll
        for (int mm = 0; mm < 2; ++mm)
#pragma unroll
            for (int nn = 0; nn < 2; ++nn) accs[mm][nn] = zero4;
#pragma unroll
        for (int nn = 0; nn < 2; ++nn) {
            bf16x8 kf0 = *(const bf16x8*)&Ks2[(wc * 32 + nn * 16 + (lane & 15)) * 72 + kof];
            bf16x8 kf1 = *(const bf16x8*)&Ks2[(wc * 32 + nn * 16 + (lane & 15)) * 72 + 32 + kof];
#pragma unroll
            for (int mm = 0; mm < 2; ++mm) {
                bf16x8 qf0 = *(const bf16x8*)&Qs[(wr * 32 + mm * 16 + (lane & 15)) * 72 + kof];
                bf16x8 qf1 = *(const bf16x8*)&Qs[(wr * 32 + mm * 16 + (lane & 15)) * 72 + 32 + kof];
                accs[mm][nn] = __builtin_amdgcn_mfma_f32_16x16x32_bf16(qf0, kf0, accs[mm][nn], 0, 0, 0);
                accs[mm][nn] = __builtin_amdgcn_mfma_f32_16x16x32_bf16(qf1, kf1, accs[mm][nn], 0, 0, 0);
            }
        }
#pragma unroll
        for (int mm = 0; mm < 2; ++mm)
#pragma unroll
            for (int nn = 0; nn < 2; ++nn)
#pragma unroll
                for (int r = 0; r < 4; ++r)
                    if (!pad2[nn]) {
                        float x = accs[mm][nn][r] + maskv[mm][nn][r];
                        wsum[mm][nn][r] += __builtin_amdgcn_exp2f(x) * rlv[mm][r];
                    }
    }

#pragma unroll
    for (int mm = 0; mm < 2; ++mm)
#pragma unroll
        for (int nn = 0; nn < 2; ++nn)
#pragma unroll
            for (int r = 0; r < 4; ++r)
                wout[((size_t)b << 20) + (size_t)(t_base + mm * 16 + r) * 1024 + s_base + nn * 16]
                    = wsum[mm][nn][r] * 0.0625f;
}

// ===================== 4. out projection GEMM (bf16 A & W, BK=64, prefetch) =====================
__global__ __launch_bounds__(256)
void out_proj_kernel(const unsigned short* __restrict__ A, const unsigned short* __restrict__ Wb,
                     const float* __restrict__ bias, float* __restrict__ out)
{
    const int j   = blockIdx.x;           // 0..255
    const int xcd = j & 7, idx = j >> 3;
    const int row0 = ((xcd << 2) + (idx >> 3)) * 128;
    const int col0 = (idx & 7) * 128;

    __shared__ __align__(16) unsigned short As[128 * 72];
    __shared__ __align__(16) unsigned short Bs[128 * 72];

    const int tid  = threadIdx.x;
    const int lane = tid & 63;
    const int wv   = tid >> 6;
    const int wr   = wv >> 1, wc = wv & 1;

    const f32x4 zero4 = {0.f, 0.f, 0.f, 0.f};
    f32x4 acc[4][4];
#pragma unroll
    for (int m = 0; m < 4; ++m)
#pragma unroll
        for (int n = 0; n < 4; ++n) acc[m][n] = zero4;

    const int srow = tid >> 1;
    const int scol = (tid & 1) << 5;
    const int arow = wr * 64 + (lane & 15);
    const int brow = wc * 64 + (lane & 15);
    const int kof  = (lane >> 4) << 3;

    const unsigned short* pa = A  + (size_t)(row0 + srow) * 1024 + scol;
    const unsigned short* pb = Wb + (size_t)(col0 + srow) * 1024 + scol;
    uint4 ra0 = *(const uint4*)(pa + 0),  ra1 = *(const uint4*)(pa + 8);
    uint4 ra2 = *(const uint4*)(pa + 16), ra3 = *(const uint4*)(pa + 24);
    uint4 rb0 = *(const uint4*)(pb + 0),  rb1 = *(const uint4*)(pb + 8);
    uint4 rb2 = *(const uint4*)(pb + 16), rb3 = *(const uint4*)(pb + 24);

    for (int k0 = 0; k0 < 1024; k0 += 64) {
        __syncthreads();
        *(uint4*)&As[srow * 72 + scol]      = ra0;
        *(uint4*)&As[srow * 72 + scol + 8]  = ra1;
        *(uint4*)&As[srow * 72 + scol + 16] = ra2;
        *(uint4*)&As[srow * 72 + scol + 24] = ra3;
        *(uint4*)&Bs[srow * 72 + scol]      = rb0;
        *(uint4*)&Bs[srow * 72 + scol + 8]  = rb1;
        *(uint4*)&Bs[srow * 72 + scol + 16] = rb2;
        *(uint4*)&Bs[srow * 72 + scol + 24] = rb3;
        __syncthreads();

        if (k0 < 960) {
            pa = A  + (size_t)(row0 + srow) * 1024 + k0 + 64 + scol;
            pb = Wb + (size_t)(col0 + srow) * 1024 + k0 + 64 + scol;
            ra0 = *(const uint4*)(pa + 0);  ra1 = *(const uint4*)(pa + 8);
            ra2 = *(const uint4*)(pa + 16); ra3 = *(const uint4*)(pa + 24);
            rb0 = *(const uint4*)(pb + 0);  rb1 = *(const uint4*)(pb + 8);
            rb2 = *(const uint4*)(pb + 16); rb3 = *(const uint4*)(pb + 24);
        }

#pragma unroll
        for (int kk = 0; kk < 2; ++kk) {
            bf16x8 af[4], bfr[4];
#pragma unroll
            for (int m = 0; m < 4; ++m)
                af[m] = *(const bf16x8*)&As[(arow + m * 16) * 72 + kk * 32 + kof];
#pragma unroll
            for (int n = 0; n < 4; ++n)
                bfr[n] = *(const bf16x8*)&Bs[(brow + n * 16) * 72 + kk * 32 + kof];
#pragma unroll
            for (int m = 0; m < 4; ++m)
#pragma unroll
                for (int n = 0; n < 4; ++n)
                    acc[m][n] = __builtin_amdgcn_mfma_f32_16x16x32_bf16(af[m], bfr[n], acc[m][n], 0, 0, 0);
        }
    }

    const int ccol = lane & 15;
    const int crow = (lane >> 4) << 2;
#pragma unroll
    for (int n = 0; n < 4; ++n) {
        const int gc   = col0 + wc * 64 + n * 16 + ccol;
        const float bv = bias[gc];
#pragma unroll
        for (int m = 0; m < 4; ++m) {
#pragma unroll
            for (int r = 0; r < 4; ++r) {
                const int gr = row0 + wr * 64 + m * 16 + crow + r;
                out[(size_t)gr * 1024 + gc] = acc[m][n][r] + bv;
            }
        }
    }
}

// ===================== host =====================
extern "C" void kernel_launch(void* const* d_in, const int* in_sizes, int n_in,
                              void* d_out, int out_size, void* d_ws, size_t ws_size,
                              hipStream_t stream)
{
    const float* query     = (const float*)d_in[0];
    const float* key       = (const float*)d_in[1];
    const float* value     = (const float*)d_in[2];
    const float* attn_mask = (const float*)d_in[3];
    const int*   padmask   = (const int*)  d_in[4];
    const float* in_proj_w = (const float*)d_in[5];
    const float* in_proj_b = (const float*)d_in[6];
    const float* out_w     = (const float*)d_in[7];
    const float* out_b     = (const float*)d_in[8];

    float* out  = (float*)d_out;
    float* wavg = out + 4194304;

    char* ws = (char*)d_ws;
    unsigned short* Qb     = (unsigned short*)(ws);              // 8 MB  [64][1024][64]
    unsigned short* Kb     = (unsigned short*)(ws + 8388608);    // 8 MB
    unsigned short* Vtb    = (unsigned short*)(ws + 16777216);   // 8 MB  [64][64][1024]
    unsigned short* Xb     = (unsigned short*)(ws + 25165824);   // 24 MB (dead after qkv)
    unsigned short* attn_o = (unsigned short*)(ws + 25165824);   // 8 MB  aliases Xb
    unsigned short* Wb     = (unsigned short*)(ws + 50331648);   // 6 MB
    unsigned short* OWb    = (unsigned short*)(ws + 56623104);   // 2 MB
    float*          rl_buf = (float*)(ws + 58720256);            // 256 KB

    cvt_kernel<<<dim3(8192), 256, 0, stream>>>(query, key, value, in_proj_w, out_w,
                                               (uint4*)Xb, (uint4*)Wb, (uint4*)OWb);
    qkv_proj_kernel<<<dim3(256, 1, 3), 256, 0, stream>>>(Xb, Wb, in_proj_b, Qb, Kb, Vtb);
    flash_kernel<<<dim3(512), 512, 0, stream>>>(Qb, Kb, Vtb, attn_mask, padmask,
                                                rl_buf, attn_o);
    wavg_kernel<<<dim3(1024), 256, 0, stream>>>(Qb, Kb, attn_mask, padmask,
                                                rl_buf, wavg);
    out_proj_kernel<<<dim3(256), 256, 0, stream>>>(attn_o, OWb, out_b, out);
}

// Round 12
// 156.220 us; speedup vs baseline: 1.0493x; 1.0493x over previous
//
#include <hip/hip_runtime.h>
#include <stdint.h>

typedef short bf16x8 __attribute__((ext_vector_type(8)));
typedef float f32x4  __attribute__((ext_vector_type(4)));

#define LOG2E_F 1.4426950408889634f
// 0.125 * log2(e): folded into Q so exp2 args need no multiply
#define QSCALE_F 0.1803368801111204f

__device__ __forceinline__ unsigned short f2bf(float f) {
    unsigned int u = __float_as_uint(f);
    return (unsigned short)((u + 0x7FFFu + ((u >> 16) & 1u)) >> 16);
}

// fast pack for non-negative, non-NaN values (round-half-up)
__device__ __forceinline__ unsigned short f2bfu(float f) {
    return (unsigned short)((__float_as_uint(f) + 0x8000u) >> 16);
}

__device__ __forceinline__ uint4 pack8(float4 a, float4 b) {
    union { unsigned short us[8]; uint4 v; } p;
    p.us[0] = f2bf(a.x); p.us[1] = f2bf(a.y); p.us[2] = f2bf(a.z); p.us[3] = f2bf(a.w);
    p.us[4] = f2bf(b.x); p.us[5] = f2bf(b.y); p.us[6] = f2bf(b.z); p.us[7] = f2bf(b.w);
    return p.v;
}

// ===================== 0. f32 -> bf16 convert (X, in_proj_w, out_w) =====================
__global__ __launch_bounds__(256)
void cvt_kernel(const float* __restrict__ q, const float* __restrict__ k,
                const float* __restrict__ v, const float* __restrict__ w,
                const float* __restrict__ ow,
                uint4* __restrict__ Xb, uint4* __restrict__ Wb, uint4* __restrict__ OWb)
{
    const unsigned g = blockIdx.x * 256 + threadIdx.x;   // 0 .. 2097151
    const float* src;
    uint4* dst;
    if (g < 1572864u) {
        dst = Xb + g;
        if (g < 524288u)        src = q + (size_t)g * 8;
        else if (g < 1048576u)  src = k + (size_t)(g - 524288u) * 8;
        else                    src = v + (size_t)(g - 1048576u) * 8;
    } else if (g < 1966080u) {
        src = w + (size_t)(g - 1572864u) * 8;
        dst = Wb + (g - 1572864u);
    } else {
        src = ow + (size_t)(g - 1966080u) * 8;
        dst = OWb + (g - 1966080u);
    }
    float4 a = *(const float4*)src;
    float4 b = *(const float4*)(src + 4);
    *dst = pack8(a, b);
}

// ===================== 0b. mask transpose: maskT[s][t] = mask[t][s] =====================
__global__ __launch_bounds__(256)
void mtr_kernel(const float* __restrict__ m, float* __restrict__ mt)
{
    __shared__ float tile[64][65];
    const int bt = (blockIdx.x & 15) << 6;   // t-block
    const int bs = (blockIdx.x >> 4) << 6;   // s-block
    const int tx = threadIdx.x & 63;
    const int ty = threadIdx.x >> 6;         // 0..3
#pragma unroll
    for (int i = 0; i < 64; i += 4)
        tile[ty + i][tx] = m[(size_t)(bt + ty + i) * 1024 + bs + tx];
    __syncthreads();
#pragma unroll
    for (int i = 0; i < 64; i += 4)
        mt[(size_t)(bs + ty + i) * 1024 + bt + tx] = tile[tx][ty + i];
}

// ===================== 1. QKV projection GEMM (bf16 in, BK=64, prefetch) =====================
__global__ __launch_bounds__(256)
void qkv_proj_kernel(const unsigned short* __restrict__ Xb, const unsigned short* __restrict__ Wb,
                     const float* __restrict__ bias,
                     unsigned short* __restrict__ Qb, unsigned short* __restrict__ Kb,
                     unsigned short* __restrict__ Vtb)
{
    const int z = blockIdx.z;
    const int j   = blockIdx.x;           // 0..255
    const int xcd = j & 7, idx = j >> 3;  // idx 0..31
    const int row0 = ((xcd << 2) + (idx >> 3)) * 128;
    const int col0 = (idx & 7) * 128;
    const int wofs = z << 10;

    const unsigned short* A = Xb + (size_t)z * 4194304;
    const unsigned short* B = Wb;

    __shared__ __align__(16) unsigned short As[128 * 72];
    __shared__ __align__(16) unsigned short Bs[128 * 72];

    const int tid  = threadIdx.x;
    const int lane = tid & 63;
    const int wv   = tid >> 6;
    const int wr   = wv >> 1, wc = wv & 1;

    const f32x4 zero4 = {0.f, 0.f, 0.f, 0.f};
    f32x4 acc[4][4];
#pragma unroll
    for (int m = 0; m < 4; ++m)
#pragma unroll
        for (int n = 0; n < 4; ++n) acc[m][n] = zero4;

    const int srow = tid >> 1;
    const int scol = (tid & 1) << 5;
    const int arow = wr * 64 + (lane & 15);
    const int brow = wc * 64 + (lane & 15);
    const int kof  = (lane >> 4) << 3;

    const unsigned short* pa = A + (size_t)(row0 + srow) * 1024 + scol;
    const unsigned short* pb = B + (size_t)(wofs + col0 + srow) * 1024 + scol;
    uint4 ra0 = *(const uint4*)(pa + 0),  ra1 = *(const uint4*)(pa + 8);
    uint4 ra2 = *(const uint4*)(pa + 16), ra3 = *(const uint4*)(pa + 24);
    uint4 rb0 = *(const uint4*)(pb + 0),  rb1 = *(const uint4*)(pb + 8);
    uint4 rb2 = *(const uint4*)(pb + 16), rb3 = *(const uint4*)(pb + 24);

    for (int k0 = 0; k0 < 1024; k0 += 64) {
        __syncthreads();
        *(uint4*)&As[srow * 72 + scol]      = ra0;
        *(uint4*)&As[srow * 72 + scol + 8]  = ra1;
        *(uint4*)&As[srow * 72 + scol + 16] = ra2;
        *(uint4*)&As[srow * 72 + scol + 24] = ra3;
        *(uint4*)&Bs[srow * 72 + scol]      = rb0;
        *(uint4*)&Bs[srow * 72 + scol + 8]  = rb1;
        *(uint4*)&Bs[srow * 72 + scol + 16] = rb2;
        *(uint4*)&Bs[srow * 72 + scol + 24] = rb3;
        __syncthreads();

        if (k0 < 960) {
            pa = A + (size_t)(row0 + srow) * 1024 + k0 + 64 + scol;
            pb = B + (size_t)(wofs + col0 + srow) * 1024 + k0 + 64 + scol;
            ra0 = *(const uint4*)(pa + 0);  ra1 = *(const uint4*)(pa + 8);
            ra2 = *(const uint4*)(pa + 16); ra3 = *(const uint4*)(pa + 24);
            rb0 = *(const uint4*)(pb + 0);  rb1 = *(const uint4*)(pb + 8);
            rb2 = *(const uint4*)(pb + 16); rb3 = *(const uint4*)(pb + 24);
        }

#pragma unroll
        for (int kk = 0; kk < 2; ++kk) {
            bf16x8 af[4], bfr[4];
#pragma unroll
            for (int m = 0; m < 4; ++m)
                af[m] = *(const bf16x8*)&As[(arow + m * 16) * 72 + kk * 32 + kof];
#pragma unroll
            for (int n = 0; n < 4; ++n)
                bfr[n] = *(const bf16x8*)&Bs[(brow + n * 16) * 72 + kk * 32 + kof];
#pragma unroll
            for (int m = 0; m < 4; ++m)
#pragma unroll
                for (int n = 0; n < 4; ++n)
                    acc[m][n] = __builtin_amdgcn_mfma_f32_16x16x32_bf16(af[m], bfr[n], acc[m][n], 0, 0, 0);
        }
    }

    const int ccol = lane & 15;
    const int crow = (lane >> 4) << 2;
#pragma unroll
    for (int n = 0; n < 4; ++n) {
        const int gc   = col0 + wc * 64 + n * 16 + ccol;
        const float bv = bias[wofs + gc];
        const int head = gc >> 6, d = gc & 63;
#pragma unroll
        for (int m = 0; m < 4; ++m) {
#pragma unroll
            for (int r = 0; r < 4; ++r) {
                const int gr = row0 + wr * 64 + m * 16 + crow + r;
                const int t  = gr >> 2, b = gr & 3;
                const int bh = (b << 4) + head;
                float vv = acc[m][n][r] + bv;
                if (z == 0)      Qb [((size_t)bh << 16) + ((size_t)t << 6) + d]  = f2bf(vv * QSCALE_F);
                else if (z == 1) Kb [((size_t)bh << 16) + ((size_t)t << 6) + d]  = f2bf(vv);
                else             Vtb[((size_t)bh << 16) + ((size_t)d << 10) + t] = f2bf(vv);
            }
        }
    }
}

// ===================== 2. flash attention (swapped QK^T, P in registers, s-permuted V, maskT) =====================
// mfma(K,Q) -> lane holds full P row for t=lane&15. PV A-fragment built lane-locally;
// V staged with s-permutation sigma. Mask read from TRANSPOSED maskT[s][t] -> coalesced;
// padmask reads become group broadcasts. No Ps LDS, cross-round dbuf, 1 barrier/round.
__global__ __launch_bounds__(512)
void flash_kernel(const unsigned short* __restrict__ Qb, const unsigned short* __restrict__ Kb,
                  const unsigned short* __restrict__ Vtb, const float* __restrict__ maskT,
                  const int* __restrict__ padmask,
                  float* __restrict__ rl_buf, unsigned short* __restrict__ attn_out)
{
    const int j   = blockIdx.x;              // 0..511
    const int xcd = j & 7, idx = j >> 3;     // idx 0..63
    const int bh  = xcd * 8 + (idx >> 3);
    const int t0  = (idx & 7) << 7;
    const int b   = bh >> 4, h = bh & 15;

    __shared__ __align__(16) unsigned short Ks[2][2][64 * 72];  // [dbuf][tile] rows=s cols=d
    __shared__ __align__(16) unsigned short Vs[2][2][64 * 72];  // rows=d cols=sigma(s)

    const int tid  = threadIdx.x;
    const int lane = tid & 63;
    const int wv   = tid >> 6;               // 0..7
    const int kof  = (lane >> 4) << 3;
    const int c16  = lane & 15;
    const int g4   = (lane >> 4) << 2;

    const unsigned short* Qbase = Qb  + ((size_t)bh << 16);
    const unsigned short* Kbase = Kb  + ((size_t)bh << 16);
    const unsigned short* Vbase = Vtb + ((size_t)bh << 16);

    bf16x8 qf[2];
#pragma unroll
    for (int kk = 0; kk < 2; ++kk)
        qf[kk] = *(const bf16x8*)(Qbase + ((size_t)(t0 + wv * 16 + c16) << 6) + kk * 32 + kof);

    const bf16x8 ones = {16256, 16256, 16256, 16256, 16256, 16256, 16256, 16256};

    const f32x4 zero4 = {0.f, 0.f, 0.f, 0.f};
    f32x4 acco[4];
#pragma unroll
    for (int nd = 0; nd < 4; ++nd) acco[nd] = zero4;
    f32x4 acc_l = zero4;

    const int srow_st = tid >> 3;            // 0..63
    const int scol_st = (tid & 7) << 3;      // 0..56

    // V scatter columns: sigma^-1 of the 8 loaded s-values -> two contiguous b64 groups
    const int bb  = scol_st & 31;
    const int hh  = scol_st & 32;
    const int cL  = hh + ((bb & 15) >> 2) * 8 + (bb >> 4) * 4;
    const int bb4 = bb + 4;
    const int cH  = hh + ((bb4 & 15) >> 2) * 8 + (bb4 >> 4) * 4;

    const int tr2 = t0 + wv * 16 + c16;      // this lane's t-row

    // ---- prologue: load round0 (tiles 0,1), stage into buf0, load round1 regs ----
    const unsigned short* kp = Kbase + ((size_t)srow_st << 6) + scol_st;
    const unsigned short* vp = Vbase + ((size_t)srow_st << 10) + scol_st;
    uint4 kA = *(const uint4*)kp;
    uint4 kB = *(const uint4*)(kp + 4096);
    uint4 vA = *(const uint4*)vp;
    uint4 vB = *(const uint4*)(vp + 64);

    {
        *(uint4*)&Ks[0][0][srow_st * 72 + scol_st] = kA;
        *(uint4*)&Ks[0][1][srow_st * 72 + scol_st] = kB;
        uint2 lo, hi;
        lo.x = vA.x; lo.y = vA.y; hi.x = vA.z; hi.y = vA.w;
        *(uint2*)&Vs[0][0][srow_st * 72 + cL] = lo;
        *(uint2*)&Vs[0][0][srow_st * 72 + cH] = hi;
        lo.x = vB.x; lo.y = vB.y; hi.x = vB.z; hi.y = vB.w;
        *(uint2*)&Vs[0][1][srow_st * 72 + cL] = lo;
        *(uint2*)&Vs[0][1][srow_st * 72 + cH] = hi;
    }
    kp = Kbase + ((size_t)(128 + srow_st) << 6) + scol_st;
    vp = Vbase + ((size_t)srow_st << 10) + 128 + scol_st;
    kA = *(const uint4*)kp;
    kB = *(const uint4*)(kp + 4096);
    vA = *(const uint4*)vp;
    vB = *(const uint4*)(vp + 64);
    __syncthreads();

    for (int rd = 0; rd < 8; ++rd) {
        const int cur = rd & 1;
        const int s0  = rd << 7;             // tile A at s0, tile B at s0+64

        if (rd < 7) {
            *(uint4*)&Ks[cur ^ 1][0][srow_st * 72 + scol_st] = kA;
            *(uint4*)&Ks[cur ^ 1][1][srow_st * 72 + scol_st] = kB;
            uint2 lo, hi;
            lo.x = vA.x; lo.y = vA.y; hi.x = vA.z; hi.y = vA.w;
            *(uint2*)&Vs[cur ^ 1][0][srow_st * 72 + cL] = lo;
            *(uint2*)&Vs[cur ^ 1][0][srow_st * 72 + cH] = hi;
            lo.x = vB.x; lo.y = vB.y; hi.x = vB.z; hi.y = vB.w;
            *(uint2*)&Vs[cur ^ 1][1][srow_st * 72 + cL] = lo;
            *(uint2*)&Vs[cur ^ 1][1][srow_st * 72 + cH] = hi;
        }
        if (rd < 6) {
            const int sn = s0 + 256;
            kp = Kbase + ((size_t)(sn + srow_st) << 6) + scol_st;
            vp = Vbase + ((size_t)srow_st << 10) + sn + scol_st;
            kA = *(const uint4*)kp;
            kB = *(const uint4*)(kp + 4096);
            vA = *(const uint4*)vp;
            vB = *(const uint4*)(vp + 64);
        }

        // QK^T swapped: accs[n] = mfma(K_frag, Q_frag) -> S[s=s0(+64)+16n+4g+r][t=tr2]
        f32x4 accsA[4], accsB[4];
#pragma unroll
        for (int n = 0; n < 4; ++n) { accsA[n] = zero4; accsB[n] = zero4; }
        __builtin_amdgcn_s_setprio(1);
#pragma unroll
        for (int n = 0; n < 4; ++n) {
            bf16x8 kfA0 = *(const bf16x8*)&Ks[cur][0][(n * 16 + c16) * 72 + kof];
            bf16x8 kfA1 = *(const bf16x8*)&Ks[cur][0][(n * 16 + c16) * 72 + 32 + kof];
            accsA[n] = __builtin_amdgcn_mfma_f32_16x16x32_bf16(kfA0, qf[0], accsA[n], 0, 0, 0);
            accsA[n] = __builtin_amdgcn_mfma_f32_16x16x32_bf16(kfA1, qf[1], accsA[n], 0, 0, 0);
            bf16x8 kfB0 = *(const bf16x8*)&Ks[cur][1][(n * 16 + c16) * 72 + kof];
            bf16x8 kfB1 = *(const bf16x8*)&Ks[cur][1][(n * 16 + c16) * 72 + 32 + kof];
            accsB[n] = __builtin_amdgcn_mfma_f32_16x16x32_bf16(kfB0, qf[0], accsB[n], 0, 0, 0);
            accsB[n] = __builtin_amdgcn_mfma_f32_16x16x32_bf16(kfB1, qf[1], accsB[n], 0, 0, 0);
        }
        __builtin_amdgcn_s_setprio(0);

#pragma unroll
        for (int tile = 0; tile < 2; ++tile) {
            const int s0t = s0 + tile * 64;
            f32x4* accs = tile ? accsB : accsA;

            // maskT reads: coalesced (16 consecutive t per lane-group); pad: group broadcast
            float mk[4][4];
            int4 pd[4];
#pragma unroll
            for (int n = 0; n < 4; ++n) {
                const int srow = s0t + n * 16 + g4;
                pd[n] = *(const int4*)(padmask + (b << 10) + srow);
#pragma unroll
                for (int r = 0; r < 4; ++r)
                    mk[n][r] = maskT[(size_t)(srow + r) * 1024 + tr2];
            }

            union { unsigned short us[16]; bf16x8 v[2]; } pk;
#pragma unroll
            for (int n = 0; n < 4; ++n) {
                float x0 = fmaf(mk[n][0], LOG2E_F, accs[n][0]);
                float x1 = fmaf(mk[n][1], LOG2E_F, accs[n][1]);
                float x2 = fmaf(mk[n][2], LOG2E_F, accs[n][2]);
                float x3 = fmaf(mk[n][3], LOG2E_F, accs[n][3]);
                if (pd[n].x) x0 = -1e30f;
                if (pd[n].y) x1 = -1e30f;
                if (pd[n].z) x2 = -1e30f;
                if (pd[n].w) x3 = -1e30f;
                pk.us[n * 4 + 0] = f2bfu(__builtin_amdgcn_exp2f(x0));
                pk.us[n * 4 + 1] = f2bfu(__builtin_amdgcn_exp2f(x1));
                pk.us[n * 4 + 2] = f2bfu(__builtin_amdgcn_exp2f(x2));
                pk.us[n * 4 + 3] = f2bfu(__builtin_amdgcn_exp2f(x3));
            }

            // PV with s-permuted V: pfrag[h] covers s-half h (n=2h,2h+1)
            __builtin_amdgcn_s_setprio(1);
#pragma unroll
            for (int hhh = 0; hhh < 2; ++hhh) {
                bf16x8 pf = pk.v[hhh];
#pragma unroll
                for (int nd = 0; nd < 4; ++nd) {
                    bf16x8 vf = *(const bf16x8*)&Vs[cur][tile][(nd * 16 + c16) * 72 + hhh * 32 + kof];
                    acco[nd] = __builtin_amdgcn_mfma_f32_16x16x32_bf16(pf, vf, acco[nd], 0, 0, 0);
                }
                acc_l = __builtin_amdgcn_mfma_f32_16x16x32_bf16(pf, ones, acc_l, 0, 0, 0);
            }
            __builtin_amdgcn_s_setprio(0);
        }

        if (rd < 7) __syncthreads();
    }

#pragma unroll
    for (int r = 0; r < 4; ++r) {
        const int t = t0 + wv * 16 + g4 + r;
        const float rl = 1.0f / acc_l[r];
        if (c16 == 0)
            rl_buf[(bh << 10) + t] = rl;
#pragma unroll
        for (int nd = 0; nd < 4; ++nd) {
            const int d = nd * 16 + c16;
            attn_out[((size_t)t * 4 + b) * 1024 + h * 64 + d] = f2bf(acco[nd][r] * rl);
        }
    }
}

// ===================== 3. weights_avg (recompute scores, all heads) =====================
__global__ __launch_bounds__(256)
void wavg_kernel(const unsigned short* __restrict__ Qb, const unsigned short* __restrict__ Kb,
                 const float* __restrict__ attn_mask, const int* __restrict__ padmask,
                 const float* __restrict__ rl_buf, float* __restrict__ wout)
{
    const int j   = blockIdx.x;              // 0..1023
    const int xcd = j & 7;
    const int b   = xcd >> 1;
    const int rr  = ((j >> 3) << 1) + (xcd & 1);  // 0..255
    const int t0  = (rr >> 4) << 6;
    const int s0  = (rr & 15) << 6;

    __shared__ __align__(16) unsigned short Qs[64 * 72];
    __shared__ __align__(16) unsigned short Ks2[64 * 72];

    const int tid  = threadIdx.x;
    const int lane = tid & 63;
    const int wv   = tid >> 6;
    const int wr   = wv >> 1, wc = wv & 1;
    const int kof  = (lane >> 4) << 3;
    const int srow_st = tid >> 2;
    const int scol_st = (tid & 3) << 4;

    const int t_base = t0 + wr * 32 + ((lane >> 4) << 2);
    const int s_base = s0 + wc * 32 + (lane & 15);

    int pad2[2];
#pragma unroll
    for (int nn = 0; nn < 2; ++nn) pad2[nn] = padmask[(b << 10) + s_base + nn * 16];

    float maskv[2][2][4];
#pragma unroll
    for (int mm = 0; mm < 2; ++mm)
#pragma unroll
        for (int r = 0; r < 4; ++r)
#pragma unroll
            for (int nn = 0; nn < 2; ++nn)
                maskv[mm][nn][r] = attn_mask[(size_t)(t_base + mm * 16 + r) * 1024 + s_base + nn * 16] * LOG2E_F;

    float wsum[2][2][4];
#pragma unroll
    for (int mm = 0; mm < 2; ++mm)
#pragma unroll
        for (int nn = 0; nn < 2; ++nn)
#pragma unroll
            for (int r = 0; r < 4; ++r) wsum[mm][nn][r] = 0.f;

    for (int h = 0; h < 16; ++h) {
        const int bh = (b << 4) + h;
        __syncthreads();
        {
            const unsigned short* qp = Qb + ((size_t)bh << 16) + ((size_t)(t0 + srow_st) << 6) + scol_st;
            *(uint4*)&Qs[srow_st * 72 + scol_st]     = *(const uint4*)qp;
            *(uint4*)&Qs[srow_st * 72 + scol_st + 8] = *(const uint4*)(qp + 8);
            const unsigned short* kp = Kb + ((size_t)bh << 16) + ((size_t)(s0 + srow_st) << 6) + scol_st;
            *(uint4*)&Ks2[srow_st * 72 + scol_st]     = *(const uint4*)kp;
            *(uint4*)&Ks2[srow_st * 72 + scol_st + 8] = *(const uint4*)(kp + 8);
        }
        __syncthreads();

        float rlv[2][4];
#pragma unroll
        for (int mm = 0; mm < 2; ++mm)
#pragma unroll
            for (int r = 0; r < 4; ++r)
                rlv[mm][r] = rl_buf[(bh << 10) + t_base + mm * 16 + r];

        const f32x4 zero4 = {0.f, 0.f, 0.f, 0.f};
        f32x4 accs[2][2];
#pragma unroll
        for (int mm = 0; mm < 2; ++mm)
#pragma unroll
            for (int nn = 0; nn < 2; ++nn) accs[mm][nn] = zero4;
#pragma unroll
        for (int nn = 0; nn < 2; ++nn) {
            bf16x8 kf0 = *(const bf16x8*)&Ks2[(wc * 32 + nn * 16 + (lane & 15)) * 72 + kof];
            bf16x8 kf1 = *(const bf16x8*)&Ks2[(wc * 32 + nn * 16 + (lane & 15)) * 72 + 32 + kof];
#pragma unroll
            for (int mm = 0; mm < 2; ++mm) {
                bf16x8 qf0 = *(const bf16x8*)&Qs[(wr * 32 + mm * 16 + (lane & 15)) * 72 + kof];
                bf16x8 qf1 = *(const bf16x8*)&Qs[(wr * 32 + mm * 16 + (lane & 15)) * 72 + 32 + kof];
                accs[mm][nn] = __builtin_amdgcn_mfma_f32_16x16x32_bf16(qf0, kf0, accs[mm][nn], 0, 0, 0);
                accs[mm][nn] = __builtin_amdgcn_mfma_f32_16x16x32_bf16(qf1, kf1, accs[mm][nn], 0, 0, 0);
            }
        }
#pragma unroll
        for (int mm = 0; mm < 2; ++mm)
#pragma unroll
            for (int nn = 0; nn < 2; ++nn)
#pragma unroll
                for (int r = 0; r < 4; ++r)
                    if (!pad2[nn]) {
                        float x = accs[mm][nn][r] + maskv[mm][nn][r];
                        wsum[mm][nn][r] += __builtin_amdgcn_exp2f(x) * rlv[mm][r];
                    }
    }

#pragma unroll
    for (int mm = 0; mm < 2; ++mm)
#pragma unroll
        for (int nn = 0; nn < 2; ++nn)
#pragma unroll
            for (int r = 0; r < 4; ++r)
                wout[((size_t)b << 20) + (size_t)(t_base + mm * 16 + r) * 1024 + s_base + nn * 16]
                    = wsum[mm][nn][r] * 0.0625f;
}

// ===================== 4. out projection GEMM (bf16 A & W, BK=64, prefetch) =====================
__global__ __launch_bounds__(256)
void out_proj_kernel(const unsigned short* __restrict__ A, const unsigned short* __restrict__ Wb,
                     const float* __restrict__ bias, float* __restrict__ out)
{
    const int j   = blockIdx.x;           // 0..255
    const int xcd = j & 7, idx = j >> 3;
    const int row0 = ((xcd << 2) + (idx >> 3)) * 128;
    const int col0 = (idx & 7) * 128;

    __shared__ __align__(16) unsigned short As[128 * 72];
    __shared__ __align__(16) unsigned short Bs[128 * 72];

    const int tid  = threadIdx.x;
    const int lane = tid & 63;
    const int wv   = tid >> 6;
    const int wr   = wv >> 1, wc = wv & 1;

    const f32x4 zero4 = {0.f, 0.f, 0.f, 0.f};
    f32x4 acc[4][4];
#pragma unroll
    for (int m = 0; m < 4; ++m)
#pragma unroll
        for (int n = 0; n < 4; ++n) acc[m][n] = zero4;

    const int srow = tid >> 1;
    const int scol = (tid & 1) << 5;
    const int arow = wr * 64 + (lane & 15);
    const int brow = wc * 64 + (lane & 15);
    const int kof  = (lane >> 4) << 3;

    const unsigned short* pa = A  + (size_t)(row0 + srow) * 1024 + scol;
    const unsigned short* pb = Wb + (size_t)(col0 + srow) * 1024 + scol;
    uint4 ra0 = *(const uint4*)(pa + 0),  ra1 = *(const uint4*)(pa + 8);
    uint4 ra2 = *(const uint4*)(pa + 16), ra3 = *(const uint4*)(pa + 24);
    uint4 rb0 = *(const uint4*)(pb + 0),  rb1 = *(const uint4*)(pb + 8);
    uint4 rb2 = *(const uint4*)(pb + 16), rb3 = *(const uint4*)(pb + 24);

    for (int k0 = 0; k0 < 1024; k0 += 64) {
        __syncthreads();
        *(uint4*)&As[srow * 72 + scol]      = ra0;
        *(uint4*)&As[srow * 72 + scol + 8]  = ra1;
        *(uint4*)&As[srow * 72 + scol + 16] = ra2;
        *(uint4*)&As[srow * 72 + scol + 24] = ra3;
        *(uint4*)&Bs[srow * 72 + scol]      = rb0;
        *(uint4*)&Bs[srow * 72 + scol + 8]  = rb1;
        *(uint4*)&Bs[srow * 72 + scol + 16] = rb2;
        *(uint4*)&Bs[srow * 72 + scol + 24] = rb3;
        __syncthreads();

        if (k0 < 960) {
            pa = A  + (size_t)(row0 + srow) * 1024 + k0 + 64 + scol;
            pb = Wb + (size_t)(col0 + srow) * 1024 + k0 + 64 + scol;
            ra0 = *(const uint4*)(pa + 0);  ra1 = *(const uint4*)(pa + 8);
            ra2 = *(const uint4*)(pa + 16); ra3 = *(const uint4*)(pa + 24);
            rb0 = *(const uint4*)(pb + 0);  rb1 = *(const uint4*)(pb + 8);
            rb2 = *(const uint4*)(pb + 16); rb3 = *(const uint4*)(pb + 24);
        }

#pragma unroll
        for (int kk = 0; kk < 2; ++kk) {
            bf16x8 af[4], bfr[4];
#pragma unroll
            for (int m = 0; m < 4; ++m)
                af[m] = *(const bf16x8*)&As[(arow + m * 16) * 72 + kk * 32 + kof];
#pragma unroll
            for (int n = 0; n < 4; ++n)
                bfr[n] = *(const bf16x8*)&Bs[(brow + n * 16) * 72 + kk * 32 + kof];
#pragma unroll
            for (int m = 0; m < 4; ++m)
#pragma unroll
                for (int n = 0; n < 4; ++n)
                    acc[m][n] = __builtin_amdgcn_mfma_f32_16x16x32_bf16(af[m], bfr[n], acc[m][n], 0, 0, 0);
        }
    }

    const int ccol = lane & 15;
    const int crow = (lane >> 4) << 2;
#pragma unroll
    for (int n = 0; n < 4; ++n) {
        const int gc   = col0 + wc * 64 + n * 16 + ccol;
        const float bv = bias[gc];
#pragma unroll
        for (int m = 0; m < 4; ++m) {
#pragma unroll
            for (int r = 0; r < 4; ++r) {
                const int gr = row0 + wr * 64 + m * 16 + crow + r;
                out[(size_t)gr * 1024 + gc] = acc[m][n][r] + bv;
            }
        }
    }
}

// ===================== host =====================
extern "C" void kernel_launch(void* const* d_in, const int* in_sizes, int n_in,
                              void* d_out, int out_size, void* d_ws, size_t ws_size,
                              hipStream_t stream)
{
    const float* query     = (const float*)d_in[0];
    const float* key       = (const float*)d_in[1];
    const float* value     = (const float*)d_in[2];
    const float* attn_mask = (const float*)d_in[3];
    const int*   padmask   = (const int*)  d_in[4];
    const float* in_proj_w = (const float*)d_in[5];
    const float* in_proj_b = (const float*)d_in[6];
    const float* out_w     = (const float*)d_in[7];
    const float* out_b     = (const float*)d_in[8];

    float* out  = (float*)d_out;
    float* wavg = out + 4194304;

    char* ws = (char*)d_ws;
    unsigned short* Qb     = (unsigned short*)(ws);              // 8 MB  [64][1024][64]
    unsigned short* Kb     = (unsigned short*)(ws + 8388608);    // 8 MB
    unsigned short* Vtb    = (unsigned short*)(ws + 16777216);   // 8 MB  [64][64][1024]
    unsigned short* Xb     = (unsigned short*)(ws + 25165824);   // 24 MB (dead after qkv)
    unsigned short* attn_o = (unsigned short*)(ws + 25165824);   // 8 MB  aliases Xb head
    float*          maskT  = (float*)(ws + 33554432);            // 4 MB  aliases Xb tail (after qkv)
    unsigned short* Wb     = (unsigned short*)(ws + 50331648);   // 6 MB
    unsigned short* OWb    = (unsigned short*)(ws + 56623104);   // 2 MB
    float*          rl_buf = (float*)(ws + 58720256);            // 256 KB

    cvt_kernel<<<dim3(8192), 256, 0, stream>>>(query, key, value, in_proj_w, out_w,
                                               (uint4*)Xb, (uint4*)Wb, (uint4*)OWb);
    qkv_proj_kernel<<<dim3(256, 1, 3), 256, 0, stream>>>(Xb, Wb, in_proj_b, Qb, Kb, Vtb);
    mtr_kernel<<<dim3(256), 256, 0, stream>>>(attn_mask, maskT);   // after qkv: Xb region now dead
    flash_kernel<<<dim3(512), 512, 0, stream>>>(Qb, Kb, Vtb, maskT, padmask,
                                                rl_buf, attn_o);
    wavg_kernel<<<dim3(1024), 256, 0, stream>>>(Qb, Kb, attn_mask, padmask,
                                                rl_buf, wavg);
    out_proj_kernel<<<dim3(256), 256, 0, stream>>>(attn_o, OWb, out_b, out);
}

// Round 13
// 154.710 us; speedup vs baseline: 1.0596x; 1.0098x over previous
//
#include <hip/hip_runtime.h>
#include <stdint.h>

typedef short bf16x8 __attribute__((ext_vector_type(8)));
typedef float f32x4  __attribute__((ext_vector_type(4)));

#define LOG2E_F 1.4426950408889634f
// 0.125 * log2(e): folded into Q so exp2 args need no multiply
#define QSCALE_F 0.1803368801111204f

__device__ __forceinline__ unsigned short f2bf(float f) {
    unsigned int u = __float_as_uint(f);
    return (unsigned short)((u + 0x7FFFu + ((u >> 16) & 1u)) >> 16);
}

// fast pack for non-negative, non-NaN values (round-half-up)
__device__ __forceinline__ unsigned short f2bfu(float f) {
    return (unsigned short)((__float_as_uint(f) + 0x8000u) >> 16);
}

__device__ __forceinline__ uint4 pack8(float4 a, float4 b) {
    union { unsigned short us[8]; uint4 v; } p;
    p.us[0] = f2bf(a.x); p.us[1] = f2bf(a.y); p.us[2] = f2bf(a.z); p.us[3] = f2bf(a.w);
    p.us[4] = f2bf(b.x); p.us[5] = f2bf(b.y); p.us[6] = f2bf(b.z); p.us[7] = f2bf(b.w);
    return p.v;
}

// ===================== 0. f32 -> bf16 convert (X, in_proj_w, out_w) =====================
__global__ __launch_bounds__(256)
void cvt_kernel(const float* __restrict__ q, const float* __restrict__ k,
                const float* __restrict__ v, const float* __restrict__ w,
                const float* __restrict__ ow,
                uint4* __restrict__ Xb, uint4* __restrict__ Wb, uint4* __restrict__ OWb)
{
    const unsigned g = blockIdx.x * 256 + threadIdx.x;   // 0 .. 2097151
    const float* src;
    uint4* dst;
    if (g < 1572864u) {
        dst = Xb + g;
        if (g < 524288u)        src = q + (size_t)g * 8;
        else if (g < 1048576u)  src = k + (size_t)(g - 524288u) * 8;
        else                    src = v + (size_t)(g - 1048576u) * 8;
    } else if (g < 1966080u) {
        src = w + (size_t)(g - 1572864u) * 8;
        dst = Wb + (g - 1572864u);
    } else {
        src = ow + (size_t)(g - 1966080u) * 8;
        dst = OWb + (g - 1966080u);
    }
    float4 a = *(const float4*)src;
    float4 b = *(const float4*)(src + 4);
    *dst = pack8(a, b);
}

// ===================== 0b. mask transpose+pack: maskT[s>>2][t][s&3] = mask[t][s] =====================
__global__ __launch_bounds__(256)
void mtr_kernel(const float* __restrict__ m, float* __restrict__ mt)
{
    __shared__ float tile[64][65];
    const int bt = (blockIdx.x & 15) << 6;   // t-block
    const int bs = (blockIdx.x >> 4) << 6;   // s-block
    const int tx = threadIdx.x & 63;
    const int ty = threadIdx.x >> 6;         // 0..3
#pragma unroll
    for (int i = 0; i < 64; i += 4)
        tile[ty + i][tx] = m[(size_t)(bt + ty + i) * 1024 + bs + tx];
    __syncthreads();
#pragma unroll
    for (int i = 0; i < 64; i += 4) {
        const int s = bs + ty + i;
        mt[(size_t)(s >> 2) * 4096 + (bt + tx) * 4 + (s & 3)] = tile[tx][ty + i];
    }
}

// ===================== 1. QKV projection GEMM (bf16 in, BK=64, prefetch) =====================
__global__ __launch_bounds__(256)
void qkv_proj_kernel(const unsigned short* __restrict__ Xb, const unsigned short* __restrict__ Wb,
                     const float* __restrict__ bias,
                     unsigned short* __restrict__ Qb, unsigned short* __restrict__ Kb,
                     unsigned short* __restrict__ Vtb)
{
    const int z = blockIdx.z;
    const int j   = blockIdx.x;           // 0..255
    const int xcd = j & 7, idx = j >> 3;  // idx 0..31
    const int row0 = ((xcd << 2) + (idx >> 3)) * 128;
    const int col0 = (idx & 7) * 128;
    const int wofs = z << 10;

    const unsigned short* A = Xb + (size_t)z * 4194304;
    const unsigned short* B = Wb;

    __shared__ __align__(16) unsigned short As[128 * 72];
    __shared__ __align__(16) unsigned short Bs[128 * 72];

    const int tid  = threadIdx.x;
    const int lane = tid & 63;
    const int wv   = tid >> 6;
    const int wr   = wv >> 1, wc = wv & 1;

    const f32x4 zero4 = {0.f, 0.f, 0.f, 0.f};
    f32x4 acc[4][4];
#pragma unroll
    for (int m = 0; m < 4; ++m)
#pragma unroll
        for (int n = 0; n < 4; ++n) acc[m][n] = zero4;

    const int srow = tid >> 1;
    const int scol = (tid & 1) << 5;
    const int arow = wr * 64 + (lane & 15);
    const int brow = wc * 64 + (lane & 15);
    const int kof  = (lane >> 4) << 3;

    const unsigned short* pa = A + (size_t)(row0 + srow) * 1024 + scol;
    const unsigned short* pb = B + (size_t)(wofs + col0 + srow) * 1024 + scol;
    uint4 ra0 = *(const uint4*)(pa + 0),  ra1 = *(const uint4*)(pa + 8);
    uint4 ra2 = *(const uint4*)(pa + 16), ra3 = *(const uint4*)(pa + 24);
    uint4 rb0 = *(const uint4*)(pb + 0),  rb1 = *(const uint4*)(pb + 8);
    uint4 rb2 = *(const uint4*)(pb + 16), rb3 = *(const uint4*)(pb + 24);

    for (int k0 = 0; k0 < 1024; k0 += 64) {
        __syncthreads();
        *(uint4*)&As[srow * 72 + scol]      = ra0;
        *(uint4*)&As[srow * 72 + scol + 8]  = ra1;
        *(uint4*)&As[srow * 72 + scol + 16] = ra2;
        *(uint4*)&As[srow * 72 + scol + 24] = ra3;
        *(uint4*)&Bs[srow * 72 + scol]      = rb0;
        *(uint4*)&Bs[srow * 72 + scol + 8]  = rb1;
        *(uint4*)&Bs[srow * 72 + scol + 16] = rb2;
        *(uint4*)&Bs[srow * 72 + scol + 24] = rb3;
        __syncthreads();

        if (k0 < 960) {
            pa = A + (size_t)(row0 + srow) * 1024 + k0 + 64 + scol;
            pb = B + (size_t)(wofs + col0 + srow) * 1024 + k0 + 64 + scol;
            ra0 = *(const uint4*)(pa + 0);  ra1 = *(const uint4*)(pa + 8);
            ra2 = *(const uint4*)(pa + 16); ra3 = *(const uint4*)(pa + 24);
            rb0 = *(const uint4*)(pb + 0);  rb1 = *(const uint4*)(pb + 8);
            rb2 = *(const uint4*)(pb + 16); rb3 = *(const uint4*)(pb + 24);
        }

#pragma unroll
        for (int kk = 0; kk < 2; ++kk) {
            bf16x8 af[4], bfr[4];
#pragma unroll
            for (int m = 0; m < 4; ++m)
                af[m] = *(const bf16x8*)&As[(arow + m * 16) * 72 + kk * 32 + kof];
#pragma unroll
            for (int n = 0; n < 4; ++n)
                bfr[n] = *(const bf16x8*)&Bs[(brow + n * 16) * 72 + kk * 32 + kof];
#pragma unroll
            for (int m = 0; m < 4; ++m)
#pragma unroll
                for (int n = 0; n < 4; ++n)
                    acc[m][n] = __builtin_amdgcn_mfma_f32_16x16x32_bf16(af[m], bfr[n], acc[m][n], 0, 0, 0);
        }
    }

    const int ccol = lane & 15;
    const int crow = (lane >> 4) << 2;
#pragma unroll
    for (int n = 0; n < 4; ++n) {
        const int gc   = col0 + wc * 64 + n * 16 + ccol;
        const float bv = bias[wofs + gc];
        const int head = gc >> 6, d = gc & 63;
#pragma unroll
        for (int m = 0; m < 4; ++m) {
#pragma unroll
            for (int r = 0; r < 4; ++r) {
                const int gr = row0 + wr * 64 + m * 16 + crow + r;
                const int t  = gr >> 2, b = gr & 3;
                const int bh = (b << 4) + head;
                float vv = acc[m][n][r] + bv;
                if (z == 0)      Qb [((size_t)bh << 16) + ((size_t)t << 6) + d]  = f2bf(vv * QSCALE_F);
                else if (z == 1) Kb [((size_t)bh << 16) + ((size_t)t << 6) + d]  = f2bf(vv);
                else             Vtb[((size_t)bh << 16) + ((size_t)d << 10) + t] = f2bf(vv);
            }
        }
    }
}

// ===================== 2. flash attention (swapped QK^T, P in registers, s-permuted V, packed maskT) =====================
// mfma(K,Q) -> lane holds full P row for t=lane&15. PV A-fragment built lane-locally;
// V staged with s-permutation sigma. Mask read from packed maskT[s>>2][t][s&3] -> one float4
// per (n,tile). No Ps LDS, cross-round dbuf, 1 barrier/round.
__global__ __launch_bounds__(512)
void flash_kernel(const unsigned short* __restrict__ Qb, const unsigned short* __restrict__ Kb,
                  const unsigned short* __restrict__ Vtb, const float* __restrict__ maskT,
                  const int* __restrict__ padmask,
                  float* __restrict__ rl_buf, unsigned short* __restrict__ attn_out)
{
    const int j   = blockIdx.x;              // 0..511
    const int xcd = j & 7, idx = j >> 3;     // idx 0..63
    const int bh  = xcd * 8 + (idx >> 3);
    const int t0  = (idx & 7) << 7;
    const int b   = bh >> 4, h = bh & 15;

    __shared__ __align__(16) unsigned short Ks[2][2][64 * 72];  // [dbuf][tile] rows=s cols=d
    __shared__ __align__(16) unsigned short Vs[2][2][64 * 72];  // rows=d cols=sigma(s)

    const int tid  = threadIdx.x;
    const int lane = tid & 63;
    const int wv   = tid >> 6;               // 0..7
    const int kof  = (lane >> 4) << 3;
    const int c16  = lane & 15;
    const int g4   = (lane >> 4) << 2;

    const unsigned short* Qbase = Qb  + ((size_t)bh << 16);
    const unsigned short* Kbase = Kb  + ((size_t)bh << 16);
    const unsigned short* Vbase = Vtb + ((size_t)bh << 16);

    bf16x8 qf[2];
#pragma unroll
    for (int kk = 0; kk < 2; ++kk)
        qf[kk] = *(const bf16x8*)(Qbase + ((size_t)(t0 + wv * 16 + c16) << 6) + kk * 32 + kof);

    const bf16x8 ones = {16256, 16256, 16256, 16256, 16256, 16256, 16256, 16256};

    const f32x4 zero4 = {0.f, 0.f, 0.f, 0.f};
    f32x4 acco[4];
#pragma unroll
    for (int nd = 0; nd < 4; ++nd) acco[nd] = zero4;
    f32x4 acc_l = zero4;

    const int srow_st = tid >> 3;            // 0..63
    const int scol_st = (tid & 7) << 3;      // 0..56

    // V scatter columns: sigma^-1 of the 8 loaded s-values -> two contiguous b64 groups
    const int bb  = scol_st & 31;
    const int hh  = scol_st & 32;
    const int cL  = hh + ((bb & 15) >> 2) * 8 + (bb >> 4) * 4;
    const int bb4 = bb + 4;
    const int cH  = hh + ((bb4 & 15) >> 2) * 8 + (bb4 >> 4) * 4;

    const int tr2 = t0 + wv * 16 + c16;      // this lane's t-row

    // ---- prologue: load round0 (tiles 0,1), stage into buf0, load round1 regs ----
    const unsigned short* kp = Kbase + ((size_t)srow_st << 6) + scol_st;
    const unsigned short* vp = Vbase + ((size_t)srow_st << 10) + scol_st;
    uint4 kA = *(const uint4*)kp;
    uint4 kB = *(const uint4*)(kp + 4096);
    uint4 vA = *(const uint4*)vp;
    uint4 vB = *(const uint4*)(vp + 64);

    {
        *(uint4*)&Ks[0][0][srow_st * 72 + scol_st] = kA;
        *(uint4*)&Ks[0][1][srow_st * 72 + scol_st] = kB;
        uint2 lo, hi;
        lo.x = vA.x; lo.y = vA.y; hi.x = vA.z; hi.y = vA.w;
        *(uint2*)&Vs[0][0][srow_st * 72 + cL] = lo;
        *(uint2*)&Vs[0][0][srow_st * 72 + cH] = hi;
        lo.x = vB.x; lo.y = vB.y; hi.x = vB.z; hi.y = vB.w;
        *(uint2*)&Vs[0][1][srow_st * 72 + cL] = lo;
        *(uint2*)&Vs[0][1][srow_st * 72 + cH] = hi;
    }
    kp = Kbase + ((size_t)(128 + srow_st) << 6) + scol_st;
    vp = Vbase + ((size_t)srow_st << 10) + 128 + scol_st;
    kA = *(const uint4*)kp;
    kB = *(const uint4*)(kp + 4096);
    vA = *(const uint4*)vp;
    vB = *(const uint4*)(vp + 64);
    __syncthreads();

    for (int rd = 0; rd < 8; ++rd) {
        const int cur = rd & 1;
        const int s0  = rd << 7;             // tile A at s0, tile B at s0+64

        if (rd < 7) {
            *(uint4*)&Ks[cur ^ 1][0][srow_st * 72 + scol_st] = kA;
            *(uint4*)&Ks[cur ^ 1][1][srow_st * 72 + scol_st] = kB;
            uint2 lo, hi;
            lo.x = vA.x; lo.y = vA.y; hi.x = vA.z; hi.y = vA.w;
            *(uint2*)&Vs[cur ^ 1][0][srow_st * 72 + cL] = lo;
            *(uint2*)&Vs[cur ^ 1][0][srow_st * 72 + cH] = hi;
            lo.x = vB.x; lo.y = vB.y; hi.x = vB.z; hi.y = vB.w;
            *(uint2*)&Vs[cur ^ 1][1][srow_st * 72 + cL] = lo;
            *(uint2*)&Vs[cur ^ 1][1][srow_st * 72 + cH] = hi;
        }
        if (rd < 6) {
            const int sn = s0 + 256;
            kp = Kbase + ((size_t)(sn + srow_st) << 6) + scol_st;
            vp = Vbase + ((size_t)srow_st << 10) + sn + scol_st;
            kA = *(const uint4*)kp;
            kB = *(const uint4*)(kp + 4096);
            vA = *(const uint4*)vp;
            vB = *(const uint4*)(vp + 64);
        }

        // QK^T swapped: accs[n] = mfma(K_frag, Q_frag) -> S[s=s0(+64)+16n+4g+r][t=tr2]
        f32x4 accsA[4], accsB[4];
#pragma unroll
        for (int n = 0; n < 4; ++n) { accsA[n] = zero4; accsB[n] = zero4; }
        __builtin_amdgcn_s_setprio(1);
#pragma unroll
        for (int n = 0; n < 4; ++n) {
            bf16x8 kfA0 = *(const bf16x8*)&Ks[cur][0][(n * 16 + c16) * 72 + kof];
            bf16x8 kfA1 = *(const bf16x8*)&Ks[cur][0][(n * 16 + c16) * 72 + 32 + kof];
            accsA[n] = __builtin_amdgcn_mfma_f32_16x16x32_bf16(kfA0, qf[0], accsA[n], 0, 0, 0);
            accsA[n] = __builtin_amdgcn_mfma_f32_16x16x32_bf16(kfA1, qf[1], accsA[n], 0, 0, 0);
            bf16x8 kfB0 = *(const bf16x8*)&Ks[cur][1][(n * 16 + c16) * 72 + kof];
            bf16x8 kfB1 = *(const bf16x8*)&Ks[cur][1][(n * 16 + c16) * 72 + 32 + kof];
            accsB[n] = __builtin_amdgcn_mfma_f32_16x16x32_bf16(kfB0, qf[0], accsB[n], 0, 0, 0);
            accsB[n] = __builtin_amdgcn_mfma_f32_16x16x32_bf16(kfB1, qf[1], accsB[n], 0, 0, 0);
        }
        __builtin_amdgcn_s_setprio(0);

#pragma unroll
        for (int tile = 0; tile < 2; ++tile) {
            const int s0t = s0 + tile * 64;
            f32x4* accs = tile ? accsB : accsA;

            // packed maskT: one float4 per n covers r=0..3; pad: group broadcast int4
            float4 mk[4];
            int4 pd[4];
#pragma unroll
            for (int n = 0; n < 4; ++n) {
                const int srow = s0t + n * 16 + g4;   // 4-aligned
                pd[n] = *(const int4*)(padmask + (b << 10) + srow);
                mk[n] = *(const float4*)(maskT + (size_t)(srow >> 2) * 4096 + tr2 * 4);
            }

            union { unsigned short us[16]; bf16x8 v[2]; } pk;
#pragma unroll
            for (int n = 0; n < 4; ++n) {
                float x0 = fmaf(mk[n].x, LOG2E_F, accs[n][0]);
                float x1 = fmaf(mk[n].y, LOG2E_F, accs[n][1]);
                float x2 = fmaf(mk[n].z, LOG2E_F, accs[n][2]);
                float x3 = fmaf(mk[n].w, LOG2E_F, accs[n][3]);
                if (pd[n].x) x0 = -1e30f;
                if (pd[n].y) x1 = -1e30f;
                if (pd[n].z) x2 = -1e30f;
                if (pd[n].w) x3 = -1e30f;
                pk.us[n * 4 + 0] = f2bfu(__builtin_amdgcn_exp2f(x0));
                pk.us[n * 4 + 1] = f2bfu(__builtin_amdgcn_exp2f(x1));
                pk.us[n * 4 + 2] = f2bfu(__builtin_amdgcn_exp2f(x2));
                pk.us[n * 4 + 3] = f2bfu(__builtin_amdgcn_exp2f(x3));
            }

            // PV with s-permuted V: pfrag[h] covers s-half h (n=2h,2h+1)
            __builtin_amdgcn_s_setprio(1);
#pragma unroll
            for (int hhh = 0; hhh < 2; ++hhh) {
                bf16x8 pf = pk.v[hhh];
#pragma unroll
                for (int nd = 0; nd < 4; ++nd) {
                    bf16x8 vf = *(const bf16x8*)&Vs[cur][tile][(nd * 16 + c16) * 72 + hhh * 32 + kof];
                    acco[nd] = __builtin_amdgcn_mfma_f32_16x16x32_bf16(pf, vf, acco[nd], 0, 0, 0);
                }
                acc_l = __builtin_amdgcn_mfma_f32_16x16x32_bf16(pf, ones, acc_l, 0, 0, 0);
            }
            __builtin_amdgcn_s_setprio(0);
        }

        if (rd < 7) __syncthreads();
    }

#pragma unroll
    for (int r = 0; r < 4; ++r) {
        const int t = t0 + wv * 16 + g4 + r;
        const float rl = 1.0f / acc_l[r];
        if (c16 == 0)
            rl_buf[(bh << 10) + t] = rl;
#pragma unroll
        for (int nd = 0; nd < 4; ++nd) {
            const int d = nd * 16 + c16;
            attn_out[((size_t)t * 4 + b) * 1024 + h * 64 + d] = f2bf(acco[nd][r] * rl);
        }
    }
}

// ===================== 3. weights_avg (recompute, 1-barrier h-pipeline dbuf) =====================
__global__ __launch_bounds__(256)
void wavg_kernel(const unsigned short* __restrict__ Qb, const unsigned short* __restrict__ Kb,
                 const float* __restrict__ attn_mask, const int* __restrict__ padmask,
                 const float* __restrict__ rl_buf, float* __restrict__ wout)
{
    const int j   = blockIdx.x;              // 0..1023
    const int xcd = j & 7;
    const int b   = xcd >> 1;
    const int rr  = ((j >> 3) << 1) + (xcd & 1);  // 0..255
    const int t0  = (rr >> 4) << 6;
    const int s0  = (rr & 15) << 6;

    __shared__ __align__(16) unsigned short Qs[2][64 * 72];
    __shared__ __align__(16) unsigned short Ks2[2][64 * 72];

    const int tid  = threadIdx.x;
    const int lane = tid & 63;
    const int wv   = tid >> 6;
    const int wr   = wv >> 1, wc = wv & 1;
    const int kof  = (lane >> 4) << 3;
    const int srow_st = tid >> 2;
    const int scol_st = (tid & 3) << 4;

    const int t_base = t0 + wr * 32 + ((lane >> 4) << 2);
    const int s_base = s0 + wc * 32 + (lane & 15);

    int pad2[2];
#pragma unroll
    for (int nn = 0; nn < 2; ++nn) pad2[nn] = padmask[(b << 10) + s_base + nn * 16];

    float maskv[2][2][4];
#pragma unroll
    for (int mm = 0; mm < 2; ++mm)
#pragma unroll
        for (int r = 0; r < 4; ++r)
#pragma unroll
            for (int nn = 0; nn < 2; ++nn)
                maskv[mm][nn][r] = attn_mask[(size_t)(t_base + mm * 16 + r) * 1024 + s_base + nn * 16] * LOG2E_F;

    float wsum[2][2][4];
#pragma unroll
    for (int mm = 0; mm < 2; ++mm)
#pragma unroll
        for (int nn = 0; nn < 2; ++nn)
#pragma unroll
            for (int r = 0; r < 4; ++r) wsum[mm][nn][r] = 0.f;

    const unsigned short* qsrc = Qb + ((size_t)(t0 + srow_st) << 6) + scol_st;
    const unsigned short* ksrc = Kb + ((size_t)(s0 + srow_st) << 6) + scol_st;
    const size_t bh0 = (size_t)(b << 4) << 16;

    // prologue: load h0 regs, stage, load h1 regs
    uint4 q0 = *(const uint4*)(qsrc + bh0);
    uint4 q1 = *(const uint4*)(qsrc + bh0 + 8);
    uint4 k0 = *(const uint4*)(ksrc + bh0);
    uint4 k1 = *(const uint4*)(ksrc + bh0 + 8);
    *(uint4*)&Qs[0][srow_st * 72 + scol_st]      = q0;
    *(uint4*)&Qs[0][srow_st * 72 + scol_st + 8]  = q1;
    *(uint4*)&Ks2[0][srow_st * 72 + scol_st]     = k0;
    *(uint4*)&Ks2[0][srow_st * 72 + scol_st + 8] = k1;
    q0 = *(const uint4*)(qsrc + bh0 + 65536);
    q1 = *(const uint4*)(qsrc + bh0 + 65536 + 8);
    k0 = *(const uint4*)(ksrc + bh0 + 65536);
    k1 = *(const uint4*)(ksrc + bh0 + 65536 + 8);
    __syncthreads();

#pragma unroll 2
    for (int h = 0; h < 16; ++h) {
        const int cur = h & 1;
        const int bh  = (b << 4) + h;

        if (h < 15) {
            *(uint4*)&Qs[cur ^ 1][srow_st * 72 + scol_st]      = q0;
            *(uint4*)&Qs[cur ^ 1][srow_st * 72 + scol_st + 8]  = q1;
            *(uint4*)&Ks2[cur ^ 1][srow_st * 72 + scol_st]     = k0;
            *(uint4*)&Ks2[cur ^ 1][srow_st * 72 + scol_st + 8] = k1;
        }
        if (h < 14) {
            const size_t of = bh0 + (size_t)(h + 2) * 65536;
            q0 = *(const uint4*)(qsrc + of);
            q1 = *(const uint4*)(qsrc + of + 8);
            k0 = *(const uint4*)(ksrc + of);
            k1 = *(const uint4*)(ksrc + of + 8);
        }

        float rlv[2][4];
#pragma unroll
        for (int mm = 0; mm < 2; ++mm)
#pragma unroll
            for (int r = 0; r < 4; ++r)
                rlv[mm][r] = rl_buf[(bh << 10) + t_base + mm * 16 + r];

        const f32x4 zero4 = {0.f, 0.f, 0.f, 0.f};
        f32x4 accs[2][2];
#pragma unroll
        for (int mm = 0; mm < 2; ++mm)
#pragma unroll
            for (int nn = 0; nn < 2; ++nn) accs[mm][nn] = zero4;
#pragma unroll
        for (int nn = 0; nn < 2; ++nn) {
            bf16x8 kf0 = *(const bf16x8*)&Ks2[cur][(wc * 32 + nn * 16 + (lane & 15)) * 72 + kof];
            bf16x8 kf1 = *(const bf16x8*)&Ks2[cur][(wc * 32 + nn * 16 + (lane & 15)) * 72 + 32 + kof];
#pragma unroll
            for (int mm = 0; mm < 2; ++mm) {
                bf16x8 qf0 = *(const bf16x8*)&Qs[cur][(wr * 32 + mm * 16 + (lane & 15)) * 72 + kof];
                bf16x8 qf1 = *(const bf16x8*)&Qs[cur][(wr * 32 + mm * 16 + (lane & 15)) * 72 + 32 + kof];
                accs[mm][nn] = __builtin_amdgcn_mfma_f32_16x16x32_bf16(qf0, kf0, accs[mm][nn], 0, 0, 0);
                accs[mm][nn] = __builtin_amdgcn_mfma_f32_16x16x32_bf16(qf1, kf1, accs[mm][nn], 0, 0, 0);
            }
        }
#pragma unroll
        for (int mm = 0; mm < 2; ++mm)
#pragma unroll
            for (int nn = 0; nn < 2; ++nn)
#pragma unroll
                for (int r = 0; r < 4; ++r)
                    if (!pad2[nn]) {
                        float x = accs[mm][nn][r] + maskv[mm][nn][r];
                        wsum[mm][nn][r] += __builtin_amdgcn_exp2f(x) * rlv[mm][r];
                    }

        if (h < 15) __syncthreads();
    }

#pragma unroll
    for (int mm = 0; mm < 2; ++mm)
#pragma unroll
        for (int nn = 0; nn < 2; ++nn)
#pragma unroll
            for (int r = 0; r < 4; ++r)
                wout[((size_t)b << 20) + (size_t)(t_base + mm * 16 + r) * 1024 + s_base + nn * 16]
                    = wsum[mm][nn][r] * 0.0625f;
}

// ===================== 4. out projection GEMM (bf16 A & W, BK=64, prefetch) =====================
__global__ __launch_bounds__(256)
void out_proj_kernel(const unsigned short* __restrict__ A, const unsigned short* __restrict__ Wb,
                     const float* __restrict__ bias, float* __restrict__ out)
{
    const int j   = blockIdx.x;           // 0..255
    const int xcd = j & 7, idx = j >> 3;
    const int row0 = ((xcd << 2) + (idx >> 3)) * 128;
    const int col0 = (idx & 7) * 128;

    __shared__ __align__(16) unsigned short As[128 * 72];
    __shared__ __align__(16) unsigned short Bs[128 * 72];

    const int tid  = threadIdx.x;
    const int lane = tid & 63;
    const int wv   = tid >> 6;
    const int wr   = wv >> 1, wc = wv & 1;

    const f32x4 zero4 = {0.f, 0.f, 0.f, 0.f};
    f32x4 acc[4][4];
#pragma unroll
    for (int m = 0; m < 4; ++m)
#pragma unroll
        for (int n = 0; n < 4; ++n) acc[m][n] = zero4;

    const int srow = tid >> 1;
    const int scol = (tid & 1) << 5;
    const int arow = wr * 64 + (lane & 15);
    const int brow = wc * 64 + (lane & 15);
    const int kof  = (lane >> 4) << 3;

    const unsigned short* pa = A  + (size_t)(row0 + srow) * 1024 + scol;
    const unsigned short* pb = Wb + (size_t)(col0 + srow) * 1024 + scol;
    uint4 ra0 = *(const uint4*)(pa + 0),  ra1 = *(const uint4*)(pa + 8);
    uint4 ra2 = *(const uint4*)(pa + 16), ra3 = *(const uint4*)(pa + 24);
    uint4 rb0 = *(const uint4*)(pb + 0),  rb1 = *(const uint4*)(pb + 8);
    uint4 rb2 = *(const uint4*)(pb + 16), rb3 = *(const uint4*)(pb + 24);

    for (int k0 = 0; k0 < 1024; k0 += 64) {
        __syncthreads();
        *(uint4*)&As[srow * 72 + scol]      = ra0;
        *(uint4*)&As[srow * 72 + scol + 8]  = ra1;
        *(uint4*)&As[srow * 72 + scol + 16] = ra2;
        *(uint4*)&As[srow * 72 + scol + 24] = ra3;
        *(uint4*)&Bs[srow * 72 + scol]      = rb0;
        *(uint4*)&Bs[srow * 72 + scol + 8]  = rb1;
        *(uint4*)&Bs[srow * 72 + scol + 16] = rb2;
        *(uint4*)&Bs[srow * 72 + scol + 24] = rb3;
        __syncthreads();

        if (k0 < 960) {
            pa = A  + (size_t)(row0 + srow) * 1024 + k0 + 64 + scol;
            pb = Wb + (size_t)(col0 + srow) * 1024 + k0 + 64 + scol;
            ra0 = *(const uint4*)(pa + 0);  ra1 = *(const uint4*)(pa + 8);
            ra2 = *(const uint4*)(pa + 16); ra3 = *(const uint4*)(pa + 24);
            rb0 = *(const uint4*)(pb + 0);  rb1 = *(const uint4*)(pb + 8);
            rb2 = *(const uint4*)(pb + 16); rb3 = *(const uint4*)(pb + 24);
        }

#pragma unroll
        for (int kk = 0; kk < 2; ++kk) {
            bf16x8 af[4], bfr[4];
#pragma unroll
            for (int m = 0; m < 4; ++m)
                af[m] = *(const bf16x8*)&As[(arow + m * 16) * 72 + kk * 32 + kof];
#pragma unroll
            for (int n = 0; n < 4; ++n)
                bfr[n] = *(const bf16x8*)&Bs[(brow + n * 16) * 72 + kk * 32 + kof];
#pragma unroll
            for (int m = 0; m < 4; ++m)
#pragma unroll
                for (int n = 0; n < 4; ++n)
                    acc[m][n] = __builtin_amdgcn_mfma_f32_16x16x32_bf16(af[m], bfr[n], acc[m][n], 0, 0, 0);
        }
    }

    const int ccol = lane & 15;
    const int crow = (lane >> 4) << 2;
#pragma unroll
    for (int n = 0; n < 4; ++n) {
        const int gc   = col0 + wc * 64 + n * 16 + ccol;
        const float bv = bias[gc];
#pragma unroll
        for (int m = 0; m < 4; ++m) {
#pragma unroll
            for (int r = 0; r < 4; ++r) {
                const int gr = row0 + wr * 64 + m * 16 + crow + r;
                out[(size_t)gr * 1024 + gc] = acc[m][n][r] + bv;
            }
        }
    }
}

// ===================== host =====================
extern "C" void kernel_launch(void* const* d_in, const int* in_sizes, int n_in,
                              void* d_out, int out_size, void* d_ws, size_t ws_size,
                              hipStream_t stream)
{
    const float* query     = (const float*)d_in[0];
    const float* key       = (const float*)d_in[1];
    const float* value     = (const float*)d_in[2];
    const float* attn_mask = (const float*)d_in[3];
    const int*   padmask   = (const int*)  d_in[4];
    const float* in_proj_w = (const float*)d_in[5];
    const float* in_proj_b = (const float*)d_in[6];
    const float* out_w     = (const float*)d_in[7];
    const float* out_b     = (const float*)d_in[8];

    float* out  = (float*)d_out;
    float* wavg = out + 4194304;

    char* ws = (char*)d_ws;
    unsigned short* Qb     = (unsigned short*)(ws);              // 8 MB  [64][1024][64]
    unsigned short* Kb     = (unsigned short*)(ws + 8388608);    // 8 MB
    unsigned short* Vtb    = (unsigned short*)(ws + 16777216);   // 8 MB  [64][64][1024]
    unsigned short* Xb     = (unsigned short*)(ws + 25165824);   // 24 MB (dead after qkv)
    unsigned short* attn_o = (unsigned short*)(ws + 25165824);   // 8 MB  aliases Xb head
    float*          maskT  = (float*)(ws + 33554432);            // 4 MB  aliases Xb tail (after qkv)
    unsigned short* Wb     = (unsigned short*)(ws + 50331648);   // 6 MB
    unsigned short* OWb    = (unsigned short*)(ws + 56623104);   // 2 MB
    float*          rl_buf = (float*)(ws + 58720256);            // 256 KB

    cvt_kernel<<<dim3(8192), 256, 0, stream>>>(query, key, value, in_proj_w, out_w,
                                               (uint4*)Xb, (uint4*)Wb, (uint4*)OWb);
    qkv_proj_kernel<<<dim3(256, 1, 3), 256, 0, stream>>>(Xb, Wb, in_proj_b, Qb, Kb, Vtb);
    mtr_kernel<<<dim3(256), 256, 0, stream>>>(attn_mask, maskT);   // after qkv: Xb region now dead
    flash_kernel<<<dim3(512), 512, 0, stream>>>(Qb, Kb, Vtb, maskT, padmask,
                                                rl_buf, attn_o);
    wavg_kernel<<<dim3(1024), 256, 0, stream>>>(Qb, Kb, attn_mask, padmask,
                                                rl_buf, wavg);
    out_proj_kernel<<<dim3(256), 256, 0, stream>>>(attn_o, OWb, out_b, out);
}

// Round 14
// 153.984 us; speedup vs baseline: 1.0646x; 1.0047x over previous
//
#include <hip/hip_runtime.h>
#include <stdint.h>

typedef short bf16x8 __attribute__((ext_vector_type(8)));
typedef float f32x4  __attribute__((ext_vector_type(4)));

#define LOG2E_F 1.4426950408889634f
// 0.125 * log2(e): folded into Q so exp2 args need no multiply
#define QSCALE_F 0.1803368801111204f

__device__ __forceinline__ unsigned short f2bf(float f) {
    unsigned int u = __float_as_uint(f);
    return (unsigned short)((u + 0x7FFFu + ((u >> 16) & 1u)) >> 16);
}

// fast pack for non-negative, non-NaN values (round-half-up)
__device__ __forceinline__ unsigned short f2bfu(float f) {
    return (unsigned short)((__float_as_uint(f) + 0x8000u) >> 16);
}

__device__ __forceinline__ uint4 pack8(float4 a, float4 b) {
    union { unsigned short us[8]; uint4 v; } p;
    p.us[0] = f2bf(a.x); p.us[1] = f2bf(a.y); p.us[2] = f2bf(a.z); p.us[3] = f2bf(a.w);
    p.us[4] = f2bf(b.x); p.us[5] = f2bf(b.y); p.us[6] = f2bf(b.z); p.us[7] = f2bf(b.w);
    return p.v;
}

// async global->LDS, 16B per lane (dest = wave-uniform base + lane*16)
__device__ __forceinline__ void gload_lds16(const unsigned short* g, unsigned short* l) {
    __builtin_amdgcn_global_load_lds(
        (const __attribute__((address_space(1))) void*)g,
        (__attribute__((address_space(3))) void*)l, 16, 0, 0);
}

// ===================== 0. f32 -> bf16 convert (X, in_proj_w, out_w) =====================
__global__ __launch_bounds__(256)
void cvt_kernel(const float* __restrict__ q, const float* __restrict__ k,
                const float* __restrict__ v, const float* __restrict__ w,
                const float* __restrict__ ow,
                uint4* __restrict__ Xb, uint4* __restrict__ Wb, uint4* __restrict__ OWb)
{
    const unsigned g = blockIdx.x * 256 + threadIdx.x;   // 0 .. 2097151
    const float* src;
    uint4* dst;
    if (g < 1572864u) {
        dst = Xb + g;
        if (g < 524288u)        src = q + (size_t)g * 8;
        else if (g < 1048576u)  src = k + (size_t)(g - 524288u) * 8;
        else                    src = v + (size_t)(g - 1048576u) * 8;
    } else if (g < 1966080u) {
        src = w + (size_t)(g - 1572864u) * 8;
        dst = Wb + (g - 1572864u);
    } else {
        src = ow + (size_t)(g - 1966080u) * 8;
        dst = OWb + (g - 1966080u);
    }
    float4 a = *(const float4*)src;
    float4 b = *(const float4*)(src + 4);
    *dst = pack8(a, b);
}

// ===================== 0b. mask transpose+pack: maskT[s>>2][t][s&3] = mask[t][s] =====================
__global__ __launch_bounds__(256)
void mtr_kernel(const float* __restrict__ m, float* __restrict__ mt)
{
    __shared__ float tile[64][65];
    const int bt = (blockIdx.x & 15) << 6;   // t-block
    const int bs = (blockIdx.x >> 4) << 6;   // s-block
    const int tx = threadIdx.x & 63;
    const int ty = threadIdx.x >> 6;         // 0..3
#pragma unroll
    for (int i = 0; i < 64; i += 4)
        tile[ty + i][tx] = m[(size_t)(bt + ty + i) * 1024 + bs + tx];
    __syncthreads();
#pragma unroll
    for (int i = 0; i < 64; i += 4) {
        const int s = bs + ty + i;
        mt[(size_t)(s >> 2) * 4096 + (bt + tx) * 4 + (s & 3)] = tile[tx][ty + i];
    }
}

// ===================== 1. QKV projection GEMM (m97 structure: BK=32, global_load_lds) =====================
__global__ __launch_bounds__(256)
void qkv_proj_kernel(const unsigned short* __restrict__ Xb, const unsigned short* __restrict__ Wb,
                     const float* __restrict__ bias,
                     unsigned short* __restrict__ Qb, unsigned short* __restrict__ Kb,
                     unsigned short* __restrict__ Vtb)
{
    const int z = blockIdx.z;
    const int j   = blockIdx.x;           // 0..255
    const int xcd = j & 7, idx = j >> 3;  // idx 0..31
    const int row0 = ((xcd << 2) + (idx >> 3)) * 128;
    const int col0 = (idx & 7) * 128;
    const int wofs = z << 10;

    const unsigned short* A = Xb + (size_t)z * 4194304;
    const unsigned short* B = Wb;

    __shared__ __align__(16) unsigned short As[128 * 32];   // linear, 8 KB
    __shared__ __align__(16) unsigned short Bs[128 * 32];

    const int tid  = threadIdx.x;
    const int lane = tid & 63;
    const int wv   = tid >> 6;
    const int wr   = wv >> 1, wc = wv & 1;
    const int c16  = lane & 15;
    const int kof  = (lane >> 4) << 3;

    const f32x4 zero4 = {0.f, 0.f, 0.f, 0.f};
    f32x4 acc[4][4];
#pragma unroll
    for (int m = 0; m < 4; ++m)
#pragma unroll
        for (int n = 0; n < 4; ++n) acc[m][n] = zero4;

    // staging geometry: LDS short idx = tid*8 (+2048 per issue) -> row = i*64 + wv*16 + lane/4, col = (lane&3)*8
    const unsigned short* gA = A + (size_t)(row0 + wv * 16 + (lane >> 2)) * 1024 + ((lane & 3) << 3);
    const unsigned short* gB = B + (size_t)(wofs + col0 + wv * 16 + (lane >> 2)) * 1024 + ((lane & 3) << 3);
    unsigned short* lA = As + tid * 8;
    unsigned short* lB = Bs + tid * 8;

    const int arow = wr * 64 + c16;
    const int brow = wc * 64 + c16;

    for (int k0 = 0; k0 < 1024; k0 += 32) {
        __syncthreads();                      // previous iter's LDS reads done
        gload_lds16(gA + k0,         lA);
        gload_lds16(gA + k0 + 65536, lA + 2048);   // +64 rows
        gload_lds16(gB + k0,         lB);
        gload_lds16(gB + k0 + 65536, lB + 2048);
        __syncthreads();                      // loads landed (vmcnt drain)

        bf16x8 af[4], bfr[4];
#pragma unroll
        for (int m = 0; m < 4; ++m)
            af[m] = *(const bf16x8*)&As[(arow + m * 16) * 32 + kof];
#pragma unroll
        for (int n = 0; n < 4; ++n)
            bfr[n] = *(const bf16x8*)&Bs[(brow + n * 16) * 32 + kof];
#pragma unroll
        for (int m = 0; m < 4; ++m)
#pragma unroll
            for (int n = 0; n < 4; ++n)
                acc[m][n] = __builtin_amdgcn_mfma_f32_16x16x32_bf16(af[m], bfr[n], acc[m][n], 0, 0, 0);
    }

    const int ccol = c16;
    const int crow = (lane >> 4) << 2;
#pragma unroll
    for (int n = 0; n < 4; ++n) {
        const int gc   = col0 + wc * 64 + n * 16 + ccol;
        const float bv = bias[wofs + gc];
        const int head = gc >> 6, d = gc & 63;
#pragma unroll
        for (int m = 0; m < 4; ++m) {
#pragma unroll
            for (int r = 0; r < 4; ++r) {
                const int gr = row0 + wr * 64 + m * 16 + crow + r;
                const int t  = gr >> 2, b = gr & 3;
                const int bh = (b << 4) + head;
                float vv = acc[m][n][r] + bv;
                if (z == 0)      Qb [((size_t)bh << 16) + ((size_t)t << 6) + d]  = f2bf(vv * QSCALE_F);
                else if (z == 1) Kb [((size_t)bh << 16) + ((size_t)t << 6) + d]  = f2bf(vv);
                else             Vtb[((size_t)bh << 16) + ((size_t)d << 10) + t] = f2bf(vv);
            }
        }
    }
}

// ===================== 2. flash attention (swapped QK^T, P in registers, s-permuted V, packed maskT) =====================
__global__ __launch_bounds__(512)
void flash_kernel(const unsigned short* __restrict__ Qb, const unsigned short* __restrict__ Kb,
                  const unsigned short* __restrict__ Vtb, const float* __restrict__ maskT,
                  const int* __restrict__ padmask,
                  float* __restrict__ rl_buf, unsigned short* __restrict__ attn_out)
{
    const int j   = blockIdx.x;              // 0..511
    const int xcd = j & 7, idx = j >> 3;     // idx 0..63
    const int bh  = xcd * 8 + (idx >> 3);
    const int t0  = (idx & 7) << 7;
    const int b   = bh >> 4, h = bh & 15;

    __shared__ __align__(16) unsigned short Ks[2][2][64 * 72];  // [dbuf][tile] rows=s cols=d
    __shared__ __align__(16) unsigned short Vs[2][2][64 * 72];  // rows=d cols=sigma(s)

    const int tid  = threadIdx.x;
    const int lane = tid & 63;
    const int wv   = tid >> 6;               // 0..7
    const int kof  = (lane >> 4) << 3;
    const int c16  = lane & 15;
    const int g4   = (lane >> 4) << 2;

    const unsigned short* Qbase = Qb  + ((size_t)bh << 16);
    const unsigned short* Kbase = Kb  + ((size_t)bh << 16);
    const unsigned short* Vbase = Vtb + ((size_t)bh << 16);

    bf16x8 qf[2];
#pragma unroll
    for (int kk = 0; kk < 2; ++kk)
        qf[kk] = *(const bf16x8*)(Qbase + ((size_t)(t0 + wv * 16 + c16) << 6) + kk * 32 + kof);

    const bf16x8 ones = {16256, 16256, 16256, 16256, 16256, 16256, 16256, 16256};

    const f32x4 zero4 = {0.f, 0.f, 0.f, 0.f};
    f32x4 acco[4];
#pragma unroll
    for (int nd = 0; nd < 4; ++nd) acco[nd] = zero4;
    f32x4 acc_l = zero4;

    const int srow_st = tid >> 3;            // 0..63
    const int scol_st = (tid & 7) << 3;      // 0..56

    // V scatter columns: sigma^-1 of the 8 loaded s-values -> two contiguous b64 groups
    const int bb  = scol_st & 31;
    const int hh  = scol_st & 32;
    const int cL  = hh + ((bb & 15) >> 2) * 8 + (bb >> 4) * 4;
    const int bb4 = bb + 4;
    const int cH  = hh + ((bb4 & 15) >> 2) * 8 + (bb4 >> 4) * 4;

    const int tr2 = t0 + wv * 16 + c16;      // this lane's t-row

    // ---- prologue: load round0 (tiles 0,1), stage into buf0, load round1 regs ----
    const unsigned short* kp = Kbase + ((size_t)srow_st << 6) + scol_st;
    const unsigned short* vp = Vbase + ((size_t)srow_st << 10) + scol_st;
    uint4 kA = *(const uint4*)kp;
    uint4 kB = *(const uint4*)(kp + 4096);
    uint4 vA = *(const uint4*)vp;
    uint4 vB = *(const uint4*)(vp + 64);

    {
        *(uint4*)&Ks[0][0][srow_st * 72 + scol_st] = kA;
        *(uint4*)&Ks[0][1][srow_st * 72 + scol_st] = kB;
        uint2 lo, hi;
        lo.x = vA.x; lo.y = vA.y; hi.x = vA.z; hi.y = vA.w;
        *(uint2*)&Vs[0][0][srow_st * 72 + cL] = lo;
        *(uint2*)&Vs[0][0][srow_st * 72 + cH] = hi;
        lo.x = vB.x; lo.y = vB.y; hi.x = vB.z; hi.y = vB.w;
        *(uint2*)&Vs[0][1][srow_st * 72 + cL] = lo;
        *(uint2*)&Vs[0][1][srow_st * 72 + cH] = hi;
    }
    kp = Kbase + ((size_t)(128 + srow_st) << 6) + scol_st;
    vp = Vbase + ((size_t)srow_st << 10) + 128 + scol_st;
    kA = *(const uint4*)kp;
    kB = *(const uint4*)(kp + 4096);
    vA = *(const uint4*)vp;
    vB = *(const uint4*)(vp + 64);
    __syncthreads();

    for (int rd = 0; rd < 8; ++rd) {
        const int cur = rd & 1;
        const int s0  = rd << 7;             // tile A at s0, tile B at s0+64

        if (rd < 7) {
            *(uint4*)&Ks[cur ^ 1][0][srow_st * 72 + scol_st] = kA;
            *(uint4*)&Ks[cur ^ 1][1][srow_st * 72 + scol_st] = kB;
            uint2 lo, hi;
            lo.x = vA.x; lo.y = vA.y; hi.x = vA.z; hi.y = vA.w;
            *(uint2*)&Vs[cur ^ 1][0][srow_st * 72 + cL] = lo;
            *(uint2*)&Vs[cur ^ 1][0][srow_st * 72 + cH] = hi;
            lo.x = vB.x; lo.y = vB.y; hi.x = vB.z; hi.y = vB.w;
            *(uint2*)&Vs[cur ^ 1][1][srow_st * 72 + cL] = lo;
            *(uint2*)&Vs[cur ^ 1][1][srow_st * 72 + cH] = hi;
        }
        if (rd < 6) {
            const int sn = s0 + 256;
            kp = Kbase + ((size_t)(sn + srow_st) << 6) + scol_st;
            vp = Vbase + ((size_t)srow_st << 10) + sn + scol_st;
            kA = *(const uint4*)kp;
            kB = *(const uint4*)(kp + 4096);
            vA = *(const uint4*)vp;
            vB = *(const uint4*)(vp + 64);
        }

        // QK^T swapped: accs[n] = mfma(K_frag, Q_frag) -> S[s=s0(+64)+16n+4g+r][t=tr2]
        f32x4 accsA[4], accsB[4];
#pragma unroll
        for (int n = 0; n < 4; ++n) { accsA[n] = zero4; accsB[n] = zero4; }
        __builtin_amdgcn_s_setprio(1);
#pragma unroll
        for (int n = 0; n < 4; ++n) {
            bf16x8 kfA0 = *(const bf16x8*)&Ks[cur][0][(n * 16 + c16) * 72 + kof];
            bf16x8 kfA1 = *(const bf16x8*)&Ks[cur][0][(n * 16 + c16) * 72 + 32 + kof];
            accsA[n] = __builtin_amdgcn_mfma_f32_16x16x32_bf16(kfA0, qf[0], accsA[n], 0, 0, 0);
            accsA[n] = __builtin_amdgcn_mfma_f32_16x16x32_bf16(kfA1, qf[1], accsA[n], 0, 0, 0);
            bf16x8 kfB0 = *(const bf16x8*)&Ks[cur][1][(n * 16 + c16) * 72 + kof];
            bf16x8 kfB1 = *(const bf16x8*)&Ks[cur][1][(n * 16 + c16) * 72 + 32 + kof];
            accsB[n] = __builtin_amdgcn_mfma_f32_16x16x32_bf16(kfB0, qf[0], accsB[n], 0, 0, 0);
            accsB[n] = __builtin_amdgcn_mfma_f32_16x16x32_bf16(kfB1, qf[1], accsB[n], 0, 0, 0);
        }
        __builtin_amdgcn_s_setprio(0);

#pragma unroll
        for (int tile = 0; tile < 2; ++tile) {
            const int s0t = s0 + tile * 64;
            f32x4* accs = tile ? accsB : accsA;

            // packed maskT: one float4 per n covers r=0..3; pad: group broadcast int4
            float4 mk[4];
            int4 pd[4];
#pragma unroll
            for (int n = 0; n < 4; ++n) {
                const int srow = s0t + n * 16 + g4;   // 4-aligned
                pd[n] = *(const int4*)(padmask + (b << 10) + srow);
                mk[n] = *(const float4*)(maskT + (size_t)(srow >> 2) * 4096 + tr2 * 4);
            }

            union { unsigned short us[16]; bf16x8 v[2]; } pk;
#pragma unroll
            for (int n = 0; n < 4; ++n) {
                float x0 = fmaf(mk[n].x, LOG2E_F, accs[n][0]);
                float x1 = fmaf(mk[n].y, LOG2E_F, accs[n][1]);
                float x2 = fmaf(mk[n].z, LOG2E_F, accs[n][2]);
                float x3 = fmaf(mk[n].w, LOG2E_F, accs[n][3]);
                if (pd[n].x) x0 = -1e30f;
                if (pd[n].y) x1 = -1e30f;
                if (pd[n].z) x2 = -1e30f;
                if (pd[n].w) x3 = -1e30f;
                pk.us[n * 4 + 0] = f2bfu(__builtin_amdgcn_exp2f(x0));
                pk.us[n * 4 + 1] = f2bfu(__builtin_amdgcn_exp2f(x1));
                pk.us[n * 4 + 2] = f2bfu(__builtin_amdgcn_exp2f(x2));
                pk.us[n * 4 + 3] = f2bfu(__builtin_amdgcn_exp2f(x3));
            }

            // PV with s-permuted V: pfrag[h] covers s-half h (n=2h,2h+1)
            __builtin_amdgcn_s_setprio(1);
#pragma unroll
            for (int hhh = 0; hhh < 2; ++hhh) {
                bf16x8 pf = pk.v[hhh];
#pragma unroll
                for (int nd = 0; nd < 4; ++nd) {
                    bf16x8 vf = *(const bf16x8*)&Vs[cur][tile][(nd * 16 + c16) * 72 + hhh * 32 + kof];
                    acco[nd] = __builtin_amdgcn_mfma_f32_16x16x32_bf16(pf, vf, acco[nd], 0, 0, 0);
                }
                acc_l = __builtin_amdgcn_mfma_f32_16x16x32_bf16(pf, ones, acc_l, 0, 0, 0);
            }
            __builtin_amdgcn_s_setprio(0);
        }

        if (rd < 7) __syncthreads();
    }

#pragma unroll
    for (int r = 0; r < 4; ++r) {
        const int t = t0 + wv * 16 + g4 + r;
        const float rl = 1.0f / acc_l[r];
        if (c16 == 0)
            rl_buf[(bh << 10) + t] = rl;
#pragma unroll
        for (int nd = 0; nd < 4; ++nd) {
            const int d = nd * 16 + c16;
            attn_out[((size_t)t * 4 + b) * 1024 + h * 64 + d] = f2bf(acco[nd][r] * rl);
        }
    }
}

// ===================== 3. weights_avg (recompute, 1-barrier h-pipeline dbuf) =====================
__global__ __launch_bounds__(256)
void wavg_kernel(const unsigned short* __restrict__ Qb, const unsigned short* __restrict__ Kb,
                 const float* __restrict__ attn_mask, const int* __restrict__ padmask,
                 const float* __restrict__ rl_buf, float* __restrict__ wout)
{
    const int j   = blockIdx.x;              // 0..1023
    const int xcd = j & 7;
    const int b   = xcd >> 1;
    const int rr  = ((j >> 3) << 1) + (xcd & 1);  // 0..255
    const int t0  = (rr >> 4) << 6;
    const int s0  = (rr & 15) << 6;

    __shared__ __align__(16) unsigned short Qs[2][64 * 72];
    __shared__ __align__(16) unsigned short Ks2[2][64 * 72];

    const int tid  = threadIdx.x;
    const int lane = tid & 63;
    const int wv   = tid >> 6;
    const int wr   = wv >> 1, wc = wv & 1;
    const int kof  = (lane >> 4) << 3;
    const int srow_st = tid >> 2;
    const int scol_st = (tid & 3) << 4;

    const int t_base = t0 + wr * 32 + ((lane >> 4) << 2);
    const int s_base = s0 + wc * 32 + (lane & 15);

    int pad2[2];
#pragma unroll
    for (int nn = 0; nn < 2; ++nn) pad2[nn] = padmask[(b << 10) + s_base + nn * 16];

    float maskv[2][2][4];
#pragma unroll
    for (int mm = 0; mm < 2; ++mm)
#pragma unroll
        for (int r = 0; r < 4; ++r)
#pragma unroll
            for (int nn = 0; nn < 2; ++nn)
                maskv[mm][nn][r] = attn_mask[(size_t)(t_base + mm * 16 + r) * 1024 + s_base + nn * 16] * LOG2E_F;

    float wsum[2][2][4];
#pragma unroll
    for (int mm = 0; mm < 2; ++mm)
#pragma unroll
        for (int nn = 0; nn < 2; ++nn)
#pragma unroll
            for (int r = 0; r < 4; ++r) wsum[mm][nn][r] = 0.f;

    const unsigned short* qsrc = Qb + ((size_t)(t0 + srow_st) << 6) + scol_st;
    const unsigned short* ksrc = Kb + ((size_t)(s0 + srow_st) << 6) + scol_st;
    const size_t bh0 = (size_t)(b << 4) << 16;

    // prologue: load h0 regs, stage, load h1 regs
    uint4 q0 = *(const uint4*)(qsrc + bh0);
    uint4 q1 = *(const uint4*)(qsrc + bh0 + 8);
    uint4 k0 = *(const uint4*)(ksrc + bh0);
    uint4 k1 = *(const uint4*)(ksrc + bh0 + 8);
    *(uint4*)&Qs[0][srow_st * 72 + scol_st]      = q0;
    *(uint4*)&Qs[0][srow_st * 72 + scol_st + 8]  = q1;
    *(uint4*)&Ks2[0][srow_st * 72 + scol_st]     = k0;
    *(uint4*)&Ks2[0][srow_st * 72 + scol_st + 8] = k1;
    q0 = *(const uint4*)(qsrc + bh0 + 65536);
    q1 = *(const uint4*)(qsrc + bh0 + 65536 + 8);
    k0 = *(const uint4*)(ksrc + bh0 + 65536);
    k1 = *(const uint4*)(ksrc + bh0 + 65536 + 8);
    __syncthreads();

#pragma unroll 2
    for (int h = 0; h < 16; ++h) {
        const int cur = h & 1;
        const int bh  = (b << 4) + h;

        if (h < 15) {
            *(uint4*)&Qs[cur ^ 1][srow_st * 72 + scol_st]      = q0;
            *(uint4*)&Qs[cur ^ 1][srow_st * 72 + scol_st + 8]  = q1;
            *(uint4*)&Ks2[cur ^ 1][srow_st * 72 + scol_st]     = k0;
            *(uint4*)&Ks2[cur ^ 1][srow_st * 72 + scol_st + 8] = k1;
        }
        if (h < 14) {
            const size_t of = bh0 + (size_t)(h + 2) * 65536;
            q0 = *(const uint4*)(qsrc + of);
            q1 = *(const uint4*)(qsrc + of + 8);
            k0 = *(const uint4*)(ksrc + of);
            k1 = *(const uint4*)(ksrc + of + 8);
        }

        float rlv[2][4];
#pragma unroll
        for (int mm = 0; mm < 2; ++mm)
#pragma unroll
            for (int r = 0; r < 4; ++r)
                rlv[mm][r] = rl_buf[(bh << 10) + t_base + mm * 16 + r];

        const f32x4 zero4 = {0.f, 0.f, 0.f, 0.f};
        f32x4 accs[2][2];
#pragma unroll
        for (int mm = 0; mm < 2; ++mm)
#pragma unroll
            for (int nn = 0; nn < 2; ++nn) accs[mm][nn] = zero4;
#pragma unroll
        for (int nn = 0; nn < 2; ++nn) {
            bf16x8 kf0 = *(const bf16x8*)&Ks2[cur][(wc * 32 + nn * 16 + (lane & 15)) * 72 + kof];
            bf16x8 kf1 = *(const bf16x8*)&Ks2[cur][(wc * 32 + nn * 16 + (lane & 15)) * 72 + 32 + kof];
#pragma unroll
            for (int mm = 0; mm < 2; ++mm) {
                bf16x8 qf0 = *(const bf16x8*)&Qs[cur][(wr * 32 + mm * 16 + (lane & 15)) * 72 + kof];
                bf16x8 qf1 = *(const bf16x8*)&Qs[cur][(wr * 32 + mm * 16 + (lane & 15)) * 72 + 32 + kof];
                accs[mm][nn] = __builtin_amdgcn_mfma_f32_16x16x32_bf16(qf0, kf0, accs[mm][nn], 0, 0, 0);
                accs[mm][nn] = __builtin_amdgcn_mfma_f32_16x16x32_bf16(qf1, kf1, accs[mm][nn], 0, 0, 0);
            }
        }
#pragma unroll
        for (int mm = 0; mm < 2; ++mm)
#pragma unroll
            for (int nn = 0; nn < 2; ++nn)
#pragma unroll
                for (int r = 0; r < 4; ++r)
                    if (!pad2[nn]) {
                        float x = accs[mm][nn][r] + maskv[mm][nn][r];
                        wsum[mm][nn][r] += __builtin_amdgcn_exp2f(x) * rlv[mm][r];
                    }

        if (h < 15) __syncthreads();
    }

#pragma unroll
    for (int mm = 0; mm < 2; ++mm)
#pragma unroll
        for (int nn = 0; nn < 2; ++nn)
#pragma unroll
            for (int r = 0; r < 4; ++r)
                wout[((size_t)b << 20) + (size_t)(t_base + mm * 16 + r) * 1024 + s_base + nn * 16]
                    = wsum[mm][nn][r] * 0.0625f;
}

// ===================== 4. out projection GEMM (m97 structure: BK=32, global_load_lds) =====================
__global__ __launch_bounds__(256)
void out_proj_kernel(const unsigned short* __restrict__ A, const unsigned short* __restrict__ Wb,
                     const float* __restrict__ bias, float* __restrict__ out)
{
    const int j   = blockIdx.x;           // 0..255
    const int xcd = j & 7, idx = j >> 3;
    const int row0 = ((xcd << 2) + (idx >> 3)) * 128;
    const int col0 = (idx & 7) * 128;

    __shared__ __align__(16) unsigned short As[128 * 32];
    __shared__ __align__(16) unsigned short Bs[128 * 32];

    const int tid  = threadIdx.x;
    const int lane = tid & 63;
    const int wv   = tid >> 6;
    const int wr   = wv >> 1, wc = wv & 1;
    const int c16  = lane & 15;
    const int kof  = (lane >> 4) << 3;

    const f32x4 zero4 = {0.f, 0.f, 0.f, 0.f};
    f32x4 acc[4][4];
#pragma unroll
    for (int m = 0; m < 4; ++m)
#pragma unroll
        for (int n = 0; n < 4; ++n) acc[m][n] = zero4;

    const unsigned short* gA = A  + (size_t)(row0 + wv * 16 + (lane >> 2)) * 1024 + ((lane & 3) << 3);
    const unsigned short* gB = Wb + (size_t)(col0 + wv * 16 + (lane >> 2)) * 1024 + ((lane & 3) << 3);
    unsigned short* lA = As + tid * 8;
    unsigned short* lB = Bs + tid * 8;

    const int arow = wr * 64 + c16;
    const int brow = wc * 64 + c16;

    for (int k0 = 0; k0 < 1024; k0 += 32) {
        __syncthreads();
        gload_lds16(gA + k0,         lA);
        gload_lds16(gA + k0 + 65536, lA + 2048);
        gload_lds16(gB + k0,         lB);
        gload_lds16(gB + k0 + 65536, lB + 2048);
        __syncthreads();

        bf16x8 af[4], bfr[4];
#pragma unroll
        for (int m = 0; m < 4; ++m)
            af[m] = *(const bf16x8*)&As[(arow + m * 16) * 32 + kof];
#pragma unroll
        for (int n = 0; n < 4; ++n)
            bfr[n] = *(const bf16x8*)&Bs[(brow + n * 16) * 32 + kof];
#pragma unroll
        for (int m = 0; m < 4; ++m)
#pragma unroll
            for (int n = 0; n < 4; ++n)
                acc[m][n] = __builtin_amdgcn_mfma_f32_16x16x32_bf16(af[m], bfr[n], acc[m][n], 0, 0, 0);
    }

    const int ccol = c16;
    const int crow = (lane >> 4) << 2;
#pragma unroll
    for (int n = 0; n < 4; ++n) {
        const int gc   = col0 + wc * 64 + n * 16 + ccol;
        const float bv = bias[gc];
#pragma unroll
        for (int m = 0; m < 4; ++m) {
#pragma unroll
            for (int r = 0; r < 4; ++r) {
                const int gr = row0 + wr * 64 + m * 16 + crow + r;
                out[(size_t)gr * 1024 + gc] = acc[m][n][r] + bv;
            }
        }
    }
}

// ===================== host =====================
extern "C" void kernel_launch(void* const* d_in, const int* in_sizes, int n_in,
                              void* d_out, int out_size, void* d_ws, size_t ws_size,
                              hipStream_t stream)
{
    const float* query     = (const float*)d_in[0];
    const float* key       = (const float*)d_in[1];
    const float* value     = (const float*)d_in[2];
    const float* attn_mask = (const float*)d_in[3];
    const int*   padmask   = (const int*)  d_in[4];
    const float* in_proj_w = (const float*)d_in[5];
    const float* in_proj_b = (const float*)d_in[6];
    const float* out_w     = (const float*)d_in[7];
    const float* out_b     = (const float*)d_in[8];

    float* out  = (float*)d_out;
    float* wavg = out + 4194304;

    char* ws = (char*)d_ws;
    unsigned short* Qb     = (unsigned short*)(ws);              // 8 MB  [64][1024][64]
    unsigned short* Kb     = (unsigned short*)(ws + 8388608);    // 8 MB
    unsigned short* Vtb    = (unsigned short*)(ws + 16777216);   // 8 MB  [64][64][1024]
    unsigned short* Xb     = (unsigned short*)(ws + 25165824);   // 24 MB (dead after qkv)
    unsigned short* attn_o = (unsigned short*)(ws + 25165824);   // 8 MB  aliases Xb head
    float*          maskT  = (float*)(ws + 33554432);            // 4 MB  aliases Xb tail (after qkv)
    unsigned short* Wb     = (unsigned short*)(ws + 50331648);   // 6 MB
    unsigned short* OWb    = (unsigned short*)(ws + 56623104);   // 2 MB
    float*          rl_buf = (float*)(ws + 58720256);            // 256 KB

    cvt_kernel<<<dim3(8192), 256, 0, stream>>>(query, key, value, in_proj_w, out_w,
                                               (uint4*)Xb, (uint4*)Wb, (uint4*)OWb);
    qkv_proj_kernel<<<dim3(256, 1, 3), 256, 0, stream>>>(Xb, Wb, in_proj_b, Qb, Kb, Vtb);
    mtr_kernel<<<dim3(256), 256, 0, stream>>>(attn_mask, maskT);   // after qkv: Xb region now dead
    flash_kernel<<<dim3(512), 512, 0, stream>>>(Qb, Kb, Vtb, maskT, padmask,
                                                rl_buf, attn_o);
    wavg_kernel<<<dim3(1024), 256, 0, stream>>>(Qb, Kb, attn_mask, padmask,
                                                rl_buf, wavg);
    out_proj_kernel<<<dim3(256), 256, 0, stream>>>(attn_o, OWb, out_b, out);
}

// Round 15
// 140.240 us; speedup vs baseline: 1.1689x; 1.0980x over previous
//
#include <hip/hip_runtime.h>
#include <stdint.h>

typedef short bf16x8 __attribute__((ext_vector_type(8)));
typedef float f32x4  __attribute__((ext_vector_type(4)));

#define LOG2E_F 1.4426950408889634f
// 0.125 * log2(e): folded into Q so exp2 args need no multiply
#define QSCALE_F 0.1803368801111204f

__device__ __forceinline__ unsigned short f2bf(float f) {
    unsigned int u = __float_as_uint(f);
    return (unsigned short)((u + 0x7FFFu + ((u >> 16) & 1u)) >> 16);
}

// fast pack for non-negative, non-NaN values (round-half-up)
__device__ __forceinline__ unsigned short f2bfu(float f) {
    return (unsigned short)((__float_as_uint(f) + 0x8000u) >> 16);
}

__device__ __forceinline__ uint4 pack8(float4 a, float4 b) {
    union { unsigned short us[8]; uint4 v; } p;
    p.us[0] = f2bf(a.x); p.us[1] = f2bf(a.y); p.us[2] = f2bf(a.z); p.us[3] = f2bf(a.w);
    p.us[4] = f2bf(b.x); p.us[5] = f2bf(b.y); p.us[6] = f2bf(b.z); p.us[7] = f2bf(b.w);
    return p.v;
}

// async global->LDS, 16B per lane
__device__ __forceinline__ void gload_lds16(const unsigned short* g, unsigned short* l) {
    __builtin_amdgcn_global_load_lds(
        (const __attribute__((address_space(1))) void*)g,
        (__attribute__((address_space(3))) void*)l, 16, 0, 0);
}

// tau^-1: R11's V column permutation (LDS col holding s_local x)
__device__ __forceinline__ int tauinv(int x) {
    const int j4 = x & 7, hh = x & 32, bb = x & 24;
    if (j4 < 4) return hh + ((bb & 15) >> 2) * 8 + (bb >> 4) * 4 + j4;
    const int b2 = bb + 4;
    return hh + ((b2 & 15) >> 2) * 8 + (b2 >> 4) * 4 + (j4 - 4);
}

// ===================== 0. f32 -> bf16 convert (X, in_proj_w, out_w) =====================
__global__ __launch_bounds__(256)
void cvt_kernel(const float* __restrict__ q, const float* __restrict__ k,
                const float* __restrict__ v, const float* __restrict__ w,
                const float* __restrict__ ow,
                uint4* __restrict__ Xb, uint4* __restrict__ Wb, uint4* __restrict__ OWb)
{
    const unsigned g = blockIdx.x * 256 + threadIdx.x;   // 0 .. 2097151
    const float* src;
    uint4* dst;
    if (g < 1572864u) {
        dst = Xb + g;
        if (g < 524288u)        src = q + (size_t)g * 8;
        else if (g < 1048576u)  src = k + (size_t)(g - 524288u) * 8;
        else                    src = v + (size_t)(g - 1048576u) * 8;
    } else if (g < 1966080u) {
        src = w + (size_t)(g - 1572864u) * 8;
        dst = Wb + (g - 1572864u);
    } else {
        src = ow + (size_t)(g - 1966080u) * 8;
        dst = OWb + (g - 1966080u);
    }
    float4 a = *(const float4*)src;
    float4 b = *(const float4*)(src + 4);
    *dst = pack8(a, b);
}

// ===================== 0b. mask transpose+pack: maskT[s>>2][t][s&3] = mask[t][s] =====================
__global__ __launch_bounds__(256)
void mtr_kernel(const float* __restrict__ m, float* __restrict__ mt)
{
    __shared__ float tile[64][65];
    const int bt = (blockIdx.x & 15) << 6;   // t-block
    const int bs = (blockIdx.x >> 4) << 6;   // s-block
    const int tx = threadIdx.x & 63;
    const int ty = threadIdx.x >> 6;         // 0..3
#pragma unroll
    for (int i = 0; i < 64; i += 4)
        tile[ty + i][tx] = m[(size_t)(bt + ty + i) * 1024 + bs + tx];
    __syncthreads();
#pragma unroll
    for (int i = 0; i < 64; i += 4) {
        const int s = bs + ty + i;
        mt[(size_t)(s >> 2) * 4096 + (bt + tx) * 4 + (s & 3)] = tile[tx][ty + i];
    }
}

// ===================== 1. QKV projection GEMM (m97 structure: BK=32, global_load_lds) =====================
// V written in flash's staged layout: Vs_flat[bh][R][d][pc][jj], pc = (tile*8 + tauinv(x)>>3) ^ (d&7)
__global__ __launch_bounds__(256)
void qkv_proj_kernel(const unsigned short* __restrict__ Xb, const unsigned short* __restrict__ Wb,
                     const float* __restrict__ bias,
                     unsigned short* __restrict__ Qb, unsigned short* __restrict__ Kb,
                     unsigned short* __restrict__ Vtb)
{
    const int z = blockIdx.z;
    const int j   = blockIdx.x;           // 0..255
    const int xcd = j & 7, idx = j >> 3;  // idx 0..31
    const int row0 = ((xcd << 2) + (idx >> 3)) * 128;
    const int col0 = (idx & 7) * 128;
    const int wofs = z << 10;

    const unsigned short* A = Xb + (size_t)z * 4194304;
    const unsigned short* B = Wb;

    __shared__ __align__(16) unsigned short As[128 * 32];   // linear, 8 KB
    __shared__ __align__(16) unsigned short Bs[128 * 32];

    const int tid  = threadIdx.x;
    const int lane = tid & 63;
    const int wv   = tid >> 6;
    const int wr   = wv >> 1, wc = wv & 1;
    const int c16  = lane & 15;
    const int kof  = (lane >> 4) << 3;

    const f32x4 zero4 = {0.f, 0.f, 0.f, 0.f};
    f32x4 acc[4][4];
#pragma unroll
    for (int m = 0; m < 4; ++m)
#pragma unroll
        for (int n = 0; n < 4; ++n) acc[m][n] = zero4;

    const unsigned short* gA = A + (size_t)(row0 + wv * 16 + (lane >> 2)) * 1024 + ((lane & 3) << 3);
    const unsigned short* gB = B + (size_t)(wofs + col0 + wv * 16 + (lane >> 2)) * 1024 + ((lane & 3) << 3);
    unsigned short* lA = As + tid * 8;
    unsigned short* lB = Bs + tid * 8;

    const int arow = wr * 64 + c16;
    const int brow = wc * 64 + c16;

    for (int k0 = 0; k0 < 1024; k0 += 32) {
        __syncthreads();
        gload_lds16(gA + k0,         lA);
        gload_lds16(gA + k0 + 65536, lA + 2048);
        gload_lds16(gB + k0,         lB);
        gload_lds16(gB + k0 + 65536, lB + 2048);
        __syncthreads();

        bf16x8 af[4], bfr[4];
#pragma unroll
        for (int m = 0; m < 4; ++m)
            af[m] = *(const bf16x8*)&As[(arow + m * 16) * 32 + kof];
#pragma unroll
        for (int n = 0; n < 4; ++n)
            bfr[n] = *(const bf16x8*)&Bs[(brow + n * 16) * 32 + kof];
#pragma unroll
        for (int m = 0; m < 4; ++m)
#pragma unroll
            for (int n = 0; n < 4; ++n)
                acc[m][n] = __builtin_amdgcn_mfma_f32_16x16x32_bf16(af[m], bfr[n], acc[m][n], 0, 0, 0);
    }

    const int ccol = c16;
    const int crow = (lane >> 4) << 2;
#pragma unroll
    for (int n = 0; n < 4; ++n) {
        const int gc   = col0 + wc * 64 + n * 16 + ccol;
        const float bv = bias[wofs + gc];
        const int head = gc >> 6, d = gc & 63;
#pragma unroll
        for (int m = 0; m < 4; ++m) {
            // t is constant across r (gr base is 4-aligned, b = r)
            const int tt = (row0 + wr * 64 + m * 16 + crow) >> 2;
            if (z == 2) {
                const int R     = tt >> 7;
                const int tileb = (tt >> 6) & 1;
                const int col   = tauinv(tt & 63);
                const int lc    = tileb * 8 + (col >> 3);
                const int jj    = col & 7;
                const int pc    = lc ^ (d & 7);
                const size_t of = ((size_t)(d) << 7) + (pc << 3) + jj;
#pragma unroll
                for (int r = 0; r < 4; ++r) {
                    const int bh = (r << 4) + head;
                    Vtb[(((size_t)bh * 8 + R) << 13) + of] = f2bf(acc[m][n][r] + bv);
                }
            } else {
#pragma unroll
                for (int r = 0; r < 4; ++r) {
                    const int bh = (r << 4) + head;
                    const float vv = acc[m][n][r] + bv;
                    if (z == 0) Qb[((size_t)bh << 16) + ((size_t)tt << 6) + d] = f2bf(vv * QSCALE_F);
                    else        Kb[((size_t)bh << 16) + ((size_t)tt << 6) + d] = f2bf(vv);
                }
            }
        }
    }
}

// ===================== 2. flash attention (swapped QK^T, P in registers, gload_lds K/V, T2 swizzle) =====================
// K: linear [64][64]-short tiles via gload_lds with pre-swizzled source (chunk ^= row&7).
// V: qkv pre-composed sigma+swizzle layout -> fully linear gload_lds; reads apply chunk^(row&7).
// LDS 64 KB -> 2 blocks/CU. 1 barrier/round (vmcnt drain covers prefetch issued a full round earlier).
__global__ __launch_bounds__(512)
void flash_kernel(const unsigned short* __restrict__ Qb, const unsigned short* __restrict__ Kb,
                  const unsigned short* __restrict__ Vtb, const float* __restrict__ maskT,
                  const int* __restrict__ padmask,
                  float* __restrict__ rl_buf, unsigned short* __restrict__ attn_out)
{
    const int j   = blockIdx.x;              // 0..511
    const int xcd = j & 7, idx = j >> 3;     // idx 0..63
    const int bh  = xcd * 8 + (idx >> 3);
    const int t0  = (idx & 7) << 7;
    const int b   = bh >> 4, h = bh & 15;

    __shared__ __align__(16) unsigned short Ks[2][2][64 * 64];  // [dbuf][tile] rows=s, 64 shorts/row
    __shared__ __align__(16) unsigned short Vs[2][64 * 128];    // [dbuf] rows=d, 128 shorts/row

    const int tid  = threadIdx.x;
    const int lane = tid & 63;
    const int wv   = tid >> 6;               // 0..7
    const int kof  = (lane >> 4) << 3;
    const int gq   = lane >> 4;              // 0..3
    const int c16  = lane & 15;
    const int g4   = gq << 2;

    const unsigned short* Qbase = Qb  + ((size_t)bh << 16);
    const unsigned short* Kbase = Kb  + ((size_t)bh << 16);
    const unsigned short* Vsig  = Vtb + ((size_t)bh << 16);   // 8 rounds * 8192 shorts

    bf16x8 qf[2];
#pragma unroll
    for (int kk = 0; kk < 2; ++kk)
        qf[kk] = *(const bf16x8*)(Qbase + ((size_t)(t0 + wv * 16 + c16) << 6) + kk * 32 + kof);

    const bf16x8 ones = {16256, 16256, 16256, 16256, 16256, 16256, 16256, 16256};

    const f32x4 zero4 = {0.f, 0.f, 0.f, 0.f};
    f32x4 acco[4];
#pragma unroll
    for (int nd = 0; nd < 4; ++nd) acco[nd] = zero4;
    f32x4 acc_l = zero4;

    // K staging source (pre-swizzled d-chunk); tile B = +64 rows = +4096 shorts
    const int strow = tid >> 3;              // 0..63
    const unsigned short* gK = Kbase + ((size_t)strow << 6) + (((tid & 7) ^ (strow & 7)) << 3);
    unsigned short* lK0a = &Ks[0][0][tid * 8];
    unsigned short* lK0b = &Ks[0][1][tid * 8];
    unsigned short* lK1a = &Ks[1][0][tid * 8];
    unsigned short* lK1b = &Ks[1][1][tid * 8];
    unsigned short* lV0  = &Vs[0][tid * 8];
    unsigned short* lV1  = &Vs[1][tid * 8];

    const int tr2 = t0 + wv * 16 + c16;      // this lane's t-row

    // prologue: stage round 0 into buf0
    gload_lds16(gK,        lK0a);
    gload_lds16(gK + 4096, lK0b);
    gload_lds16(Vsig + tid * 8,        lV0);
    gload_lds16(Vsig + 4096 + tid * 8, lV0 + 4096);
    __syncthreads();

    for (int rd = 0; rd < 8; ++rd) {
        const int cur = rd & 1;
        const int s0  = rd << 7;             // tile A at s0, tile B at s0+64

        if (rd < 7) {                        // prefetch round rd+1 into the other buffer
            const size_t kofs = (size_t)(s0 + 128) << 6;
            gload_lds16(gK + kofs,        cur ? lK0a : lK1a);
            gload_lds16(gK + kofs + 4096, cur ? lK0b : lK1b);
            const size_t vofs = (size_t)(rd + 1) << 13;
            gload_lds16(Vsig + vofs + tid * 8,        cur ? lV0 : lV1);
            gload_lds16(Vsig + vofs + 4096 + tid * 8, (cur ? lV0 : lV1) + 4096);
        }

        // QK^T swapped: accs[n] = mfma(K_frag, Q_frag) -> S[s][t=tr2]; K read swizzled
        f32x4 accsA[4], accsB[4];
#pragma unroll
        for (int n = 0; n < 4; ++n) { accsA[n] = zero4; accsB[n] = zero4; }
        __builtin_amdgcn_s_setprio(1);
#pragma unroll
        for (int n = 0; n < 4; ++n) {
            const int rowK = n * 16 + c16;
            const int swzK = rowK & 7;
            const int o0 = rowK * 64 + ((gq ^ swzK) << 3);
            const int o1 = rowK * 64 + (((4 + gq) ^ swzK) << 3);
            bf16x8 kfA0 = *(const bf16x8*)&Ks[cur][0][o0];
            bf16x8 kfA1 = *(const bf16x8*)&Ks[cur][0][o1];
            accsA[n] = __builtin_amdgcn_mfma_f32_16x16x32_bf16(kfA0, qf[0], accsA[n], 0, 0, 0);
            accsA[n] = __builtin_amdgcn_mfma_f32_16x16x32_bf16(kfA1, qf[1], accsA[n], 0, 0, 0);
            bf16x8 kfB0 = *(const bf16x8*)&Ks[cur][1][o0];
            bf16x8 kfB1 = *(const bf16x8*)&Ks[cur][1][o1];
            accsB[n] = __builtin_amdgcn_mfma_f32_16x16x32_bf16(kfB0, qf[0], accsB[n], 0, 0, 0);
            accsB[n] = __builtin_amdgcn_mfma_f32_16x16x32_bf16(kfB1, qf[1], accsB[n], 0, 0, 0);
        }
        __builtin_amdgcn_s_setprio(0);

#pragma unroll
        for (int tile = 0; tile < 2; ++tile) {
            const int s0t = s0 + tile * 64;
            f32x4* accs = tile ? accsB : accsA;

            float4 mk[4];
            int4 pd[4];
#pragma unroll
            for (int n = 0; n < 4; ++n) {
                const int srow = s0t + n * 16 + g4;   // 4-aligned
                pd[n] = *(const int4*)(padmask + (b << 10) + srow);
                mk[n] = *(const float4*)(maskT + (size_t)(srow >> 2) * 4096 + tr2 * 4);
            }

            union { unsigned short us[16]; bf16x8 v[2]; } pk;
#pragma unroll
            for (int n = 0; n < 4; ++n) {
                float x0 = fmaf(mk[n].x, LOG2E_F, accs[n][0]);
                float x1 = fmaf(mk[n].y, LOG2E_F, accs[n][1]);
                float x2 = fmaf(mk[n].z, LOG2E_F, accs[n][2]);
                float x3 = fmaf(mk[n].w, LOG2E_F, accs[n][3]);
                if (pd[n].x) x0 = -1e30f;
                if (pd[n].y) x1 = -1e30f;
                if (pd[n].z) x2 = -1e30f;
                if (pd[n].w) x3 = -1e30f;
                pk.us[n * 4 + 0] = f2bfu(__builtin_amdgcn_exp2f(x0));
                pk.us[n * 4 + 1] = f2bfu(__builtin_amdgcn_exp2f(x1));
                pk.us[n * 4 + 2] = f2bfu(__builtin_amdgcn_exp2f(x2));
                pk.us[n * 4 + 3] = f2bfu(__builtin_amdgcn_exp2f(x3));
            }

            // PV: V read with chunk swizzle (lc = tile*8 + hhh*4 + gq, pc = lc ^ (row&7))
            __builtin_amdgcn_s_setprio(1);
#pragma unroll
            for (int hhh = 0; hhh < 2; ++hhh) {
                bf16x8 pf = pk.v[hhh];
                const int lc = tile * 8 + hhh * 4 + gq;
#pragma unroll
                for (int nd = 0; nd < 4; ++nd) {
                    const int rowV = nd * 16 + c16;
                    bf16x8 vf = *(const bf16x8*)&Vs[cur][rowV * 128 + ((lc ^ (rowV & 7)) << 3)];
                    acco[nd] = __builtin_amdgcn_mfma_f32_16x16x32_bf16(pf, vf, acco[nd], 0, 0, 0);
                }
                acc_l = __builtin_amdgcn_mfma_f32_16x16x32_bf16(pf, ones, acc_l, 0, 0, 0);
            }
            __builtin_amdgcn_s_setprio(0);
        }

        if (rd < 7) __syncthreads();
    }

#pragma unroll
    for (int r = 0; r < 4; ++r) {
        const int t = t0 + wv * 16 + g4 + r;
        const float rl = 1.0f / acc_l[r];
        if (c16 == 0)
            rl_buf[(bh << 10) + t] = rl;
#pragma unroll
        for (int nd = 0; nd < 4; ++nd) {
            const int d = nd * 16 + c16;
            attn_out[((size_t)t * 4 + b) * 1024 + h * 64 + d] = f2bf(acco[nd][r] * rl);
        }
    }
}

// ===================== 3. weights_avg (recompute, 1-barrier h-pipeline dbuf) =====================
__global__ __launch_bounds__(256)
void wavg_kernel(const unsigned short* __restrict__ Qb, const unsigned short* __restrict__ Kb,
                 const float* __restrict__ attn_mask, const int* __restrict__ padmask,
                 const float* __restrict__ rl_buf, float* __restrict__ wout)
{
    const int j   = blockIdx.x;              // 0..1023
    const int xcd = j & 7;
    const int b   = xcd >> 1;
    const int rr  = ((j >> 3) << 1) + (xcd & 1);  // 0..255
    const int t0  = (rr >> 4) << 6;
    const int s0  = (rr & 15) << 6;

    __shared__ __align__(16) unsigned short Qs[2][64 * 72];
    __shared__ __align__(16) unsigned short Ks2[2][64 * 72];

    const int tid  = threadIdx.x;
    const int lane = tid & 63;
    const int wv   = tid >> 6;
    const int wr   = wv >> 1, wc = wv & 1;
    const int kof  = (lane >> 4) << 3;
    const int srow_st = tid >> 2;
    const int scol_st = (tid & 3) << 4;

    const int t_base = t0 + wr * 32 + ((lane >> 4) << 2);
    const int s_base = s0 + wc * 32 + (lane & 15);

    int pad2[2];
#pragma unroll
    for (int nn = 0; nn < 2; ++nn) pad2[nn] = padmask[(b << 10) + s_base + nn * 16];

    float maskv[2][2][4];
#pragma unroll
    for (int mm = 0; mm < 2; ++mm)
#pragma unroll
        for (int r = 0; r < 4; ++r)
#pragma unroll
            for (int nn = 0; nn < 2; ++nn)
                maskv[mm][nn][r] = attn_mask[(size_t)(t_base + mm * 16 + r) * 1024 + s_base + nn * 16] * LOG2E_F;

    float wsum[2][2][4];
#pragma unroll
    for (int mm = 0; mm < 2; ++mm)
#pragma unroll
        for (int nn = 0; nn < 2; ++nn)
#pragma unroll
            for (int r = 0; r < 4; ++r) wsum[mm][nn][r] = 0.f;

    const unsigned short* qsrc = Qb + ((size_t)(t0 + srow_st) << 6) + scol_st;
    const unsigned short* ksrc = Kb + ((size_t)(s0 + srow_st) << 6) + scol_st;
    const size_t bh0 = (size_t)(b << 4) << 16;

    uint4 q0 = *(const uint4*)(qsrc + bh0);
    uint4 q1 = *(const uint4*)(qsrc + bh0 + 8);
    uint4 k0 = *(const uint4*)(ksrc + bh0);
    uint4 k1 = *(const uint4*)(ksrc + bh0 + 8);
    *(uint4*)&Qs[0][srow_st * 72 + scol_st]      = q0;
    *(uint4*)&Qs[0][srow_st * 72 + scol_st + 8]  = q1;
    *(uint4*)&Ks2[0][srow_st * 72 + scol_st]     = k0;
    *(uint4*)&Ks2[0][srow_st * 72 + scol_st + 8] = k1;
    q0 = *(const uint4*)(qsrc + bh0 + 65536);
    q1 = *(const uint4*)(qsrc + bh0 + 65536 + 8);
    k0 = *(const uint4*)(ksrc + bh0 + 65536);
    k1 = *(const uint4*)(ksrc + bh0 + 65536 + 8);
    __syncthreads();

#pragma unroll 2
    for (int h = 0; h < 16; ++h) {
        const int cur = h & 1;
        const int bh  = (b << 4) + h;

        if (h < 15) {
            *(uint4*)&Qs[cur ^ 1][srow_st * 72 + scol_st]      = q0;
            *(uint4*)&Qs[cur ^ 1][srow_st * 72 + scol_st + 8]  = q1;
            *(uint4*)&Ks2[cur ^ 1][srow_st * 72 + scol_st]     = k0;
            *(uint4*)&Ks2[cur ^ 1][srow_st * 72 + scol_st + 8] = k1;
        }
        if (h < 14) {
            const size_t of = bh0 + (size_t)(h + 2) * 65536;
            q0 = *(const uint4*)(qsrc + of);
            q1 = *(const uint4*)(qsrc + of + 8);
            k0 = *(const uint4*)(ksrc + of);
            k1 = *(const uint4*)(ksrc + of + 8);
        }

        float rlv[2][4];
#pragma unroll
        for (int mm = 0; mm < 2; ++mm)
#pragma unroll
            for (int r = 0; r < 4; ++r)
                rlv[mm][r] = rl_buf[(bh << 10) + t_base + mm * 16 + r];

        const f32x4 zero4 = {0.f, 0.f, 0.f, 0.f};
        f32x4 accs[2][2];
#pragma unroll
        for (int mm = 0; mm < 2; ++mm)
#pragma unroll
            for (int nn = 0; nn < 2; ++nn) accs[mm][nn] = zero4;
#pragma unroll
        for (int nn = 0; nn < 2; ++nn) {
            bf16x8 kf0 = *(const bf16x8*)&Ks2[cur][(wc * 32 + nn * 16 + (lane & 15)) * 72 + kof];
            bf16x8 kf1 = *(const bf16x8*)&Ks2[cur][(wc * 32 + nn * 16 + (lane & 15)) * 72 + 32 + kof];
#pragma unroll
            for (int mm = 0; mm < 2; ++mm) {
                bf16x8 qf0 = *(const bf16x8*)&Qs[cur][(wr * 32 + mm * 16 + (lane & 15)) * 72 + kof];
                bf16x8 qf1 = *(const bf16x8*)&Qs[cur][(wr * 32 + mm * 16 + (lane & 15)) * 72 + 32 + kof];
                accs[mm][nn] = __builtin_amdgcn_mfma_f32_16x16x32_bf16(qf0, kf0, accs[mm][nn], 0, 0, 0);
                accs[mm][nn] = __builtin_amdgcn_mfma_f32_16x16x32_bf16(qf1, kf1, accs[mm][nn], 0, 0, 0);
            }
        }
#pragma unroll
        for (int mm = 0; mm < 2; ++mm)
#pragma unroll
            for (int nn = 0; nn < 2; ++nn)
#pragma unroll
                for (int r = 0; r < 4; ++r)
                    if (!pad2[nn]) {
                        float x = accs[mm][nn][r] + maskv[mm][nn][r];
                        wsum[mm][nn][r] += __builtin_amdgcn_exp2f(x) * rlv[mm][r];
                    }

        if (h < 15) __syncthreads();
    }

#pragma unroll
    for (int mm = 0; mm < 2; ++mm)
#pragma unroll
        for (int nn = 0; nn < 2; ++nn)
#pragma unroll
            for (int r = 0; r < 4; ++r)
                wout[((size_t)b << 20) + (size_t)(t_base + mm * 16 + r) * 1024 + s_base + nn * 16]
                    = wsum[mm][nn][r] * 0.0625f;
}

// ===================== 4. out projection GEMM (m97 structure: BK=32, global_load_lds) =====================
__global__ __launch_bounds__(256)
void out_proj_kernel(const unsigned short* __restrict__ A, const unsigned short* __restrict__ Wb,
                     const float* __restrict__ bias, float* __restrict__ out)
{
    const int j   = blockIdx.x;           // 0..255
    const int xcd = j & 7, idx = j >> 3;
    const int row0 = ((xcd << 2) + (idx >> 3)) * 128;
    const int col0 = (idx & 7) * 128;

    __shared__ __align__(16) unsigned short As[128 * 32];
    __shared__ __align__(16) unsigned short Bs[128 * 32];

    const int tid  = threadIdx.x;
    const int lane = tid & 63;
    const int wv   = tid >> 6;
    const int wr   = wv >> 1, wc = wv & 1;
    const int c16  = lane & 15;
    const int kof  = (lane >> 4) << 3;

    const f32x4 zero4 = {0.f, 0.f, 0.f, 0.f};
    f32x4 acc[4][4];
#pragma unroll
    for (int m = 0; m < 4; ++m)
#pragma unroll
        for (int n = 0; n < 4; ++n) acc[m][n] = zero4;

    const unsigned short* gA = A  + (size_t)(row0 + wv * 16 + (lane >> 2)) * 1024 + ((lane & 3) << 3);
    const unsigned short* gB = Wb + (size_t)(col0 + wv * 16 + (lane >> 2)) * 1024 + ((lane & 3) << 3);
    unsigned short* lA = As + tid * 8;
    unsigned short* lB = Bs + tid * 8;

    const int arow = wr * 64 + c16;
    const int brow = wc * 64 + c16;

    for (int k0 = 0; k0 < 1024; k0 += 32) {
        __syncthreads();
        gload_lds16(gA + k0,         lA);
        gload_lds16(gA + k0 + 65536, lA + 2048);
        gload_lds16(gB + k0,         lB);
        gload_lds16(gB + k0 + 65536, lB + 2048);
        __syncthreads();

        bf16x8 af[4], bfr[4];
#pragma unroll
        for (int m = 0; m < 4; ++m)
            af[m] = *(const bf16x8*)&As[(arow + m * 16) * 32 + kof];
#pragma unroll
        for (int n = 0; n < 4; ++n)
            bfr[n] = *(const bf16x8*)&Bs[(brow + n * 16) * 32 + kof];
#pragma unroll
        for (int m = 0; m < 4; ++m)
#pragma unroll
            for (int n = 0; n < 4; ++n)
                acc[m][n] = __builtin_amdgcn_mfma_f32_16x16x32_bf16(af[m], bfr[n], acc[m][n], 0, 0, 0);
    }

    const int ccol = c16;
    const int crow = (lane >> 4) << 2;
#pragma unroll
    for (int n = 0; n < 4; ++n) {
        const int gc   = col0 + wc * 64 + n * 16 + ccol;
        const float bv = bias[gc];
#pragma unroll
        for (int m = 0; m < 4; ++m) {
#pragma unroll
            for (int r = 0; r < 4; ++r) {
                const int gr = row0 + wr * 64 + m * 16 + crow + r;
                out[(size_t)gr * 1024 + gc] = acc[m][n][r] + bv;
            }
        }
    }
}

// ===================== host =====================
extern "C" void kernel_launch(void* const* d_in, const int* in_sizes, int n_in,
                              void* d_out, int out_size, void* d_ws, size_t ws_size,
                              hipStream_t stream)
{
    const float* query     = (const float*)d_in[0];
    const float* key       = (const float*)d_in[1];
    const float* value     = (const float*)d_in[2];
    const float* attn_mask = (const float*)d_in[3];
    const int*   padmask   = (const int*)  d_in[4];
    const float* in_proj_w = (const float*)d_in[5];
    const float* in_proj_b = (const float*)d_in[6];
    const float* out_w     = (const float*)d_in[7];
    const float* out_b     = (const float*)d_in[8];

    float* out  = (float*)d_out;
    float* wavg = out + 4194304;

    char* ws = (char*)d_ws;
    unsigned short* Qb     = (unsigned short*)(ws);              // 8 MB  [64][1024][64]
    unsigned short* Kb     = (unsigned short*)(ws + 8388608);    // 8 MB
    unsigned short* Vtb    = (unsigned short*)(ws + 16777216);   // 8 MB  [64 bh][8 R][64 d][128]
    unsigned short* Xb     = (unsigned short*)(ws + 25165824);   // 24 MB (dead after qkv)
    unsigned short* attn_o = (unsigned short*)(ws + 25165824);   // 8 MB  aliases Xb head
    float*          maskT  = (float*)(ws + 33554432);            // 4 MB  aliases Xb tail (after qkv)
    unsigned short* Wb     = (unsigned short*)(ws + 50331648);   // 6 MB
    unsigned short* OWb    = (unsigned short*)(ws + 56623104);   // 2 MB
    float*          rl_buf = (float*)(ws + 58720256);            // 256 KB

    cvt_kernel<<<dim3(8192), 256, 0, stream>>>(query, key, value, in_proj_w, out_w,
                                               (uint4*)Xb, (uint4*)Wb, (uint4*)OWb);
    qkv_proj_kernel<<<dim3(256, 1, 3), 256, 0, stream>>>(Xb, Wb, in_proj_b, Qb, Kb, Vtb);
    mtr_kernel<<<dim3(256), 256, 0, stream>>>(attn_mask, maskT);   // after qkv: Xb region now dead
    flash_kernel<<<dim3(512), 512, 0, stream>>>(Qb, Kb, Vtb, maskT, padmask,
                                                rl_buf, attn_o);
    wavg_kernel<<<dim3(1024), 256, 0, stream>>>(Qb, Kb, attn_mask, padmask,
                                                rl_buf, wavg);
    out_proj_kernel<<<dim3(256), 256, 0, stream>>>(attn_o, OWb, out_b, out);
}